// Round 7
// baseline (5205.636 us; speedup 1.0000x reference)
//
#include <hip/hip_runtime.h>
#include <hip/hip_bf16.h>
#include <math.h>

#define NBOX 4096
#define HDIM 128
#define G3   384   // 3*H

typedef _Float16 half2v __attribute__((ext_vector_type(2)));

__device__ __forceinline__ float sigm(float x) { return 1.f / (1.f + expf(-x)); }
__device__ __forceinline__ float sigm_fast(float x) {
    return __builtin_amdgcn_rcpf(1.f + __expf(-x));
}
__device__ __forceinline__ float tanh_fast(float x) {
    x = fminf(15.f, fmaxf(-15.f, x));
    const float e2 = __expf(2.f * x);
    return (e2 - 1.f) * __builtin_amdgcn_rcpf(e2 + 1.f);
}
// DPP quad-perm broadcasts: quad lane k -> all 4 lanes of the quad
__device__ __forceinline__ float bcast_q0(float x) {
    return __int_as_float(__builtin_amdgcn_mov_dpp(__float_as_int(x), 0x00, 0xF, 0xF, false));
}
__device__ __forceinline__ float bcast_q1(float x) {
    return __int_as_float(__builtin_amdgcn_mov_dpp(__float_as_int(x), 0x55, 0xF, 0xF, false));
}
// v_dot2_f32_f16: exact f16 products, f32 accumulate
__device__ __forceinline__ float fdot2(unsigned int h2, unsigned int w2, float acc) {
    return __builtin_amdgcn_fdot2(__builtin_bit_cast(half2v, h2),
                                  __builtin_bit_cast(half2v, w2), acc, false);
}

// C[M,N] = act(A[M,K] @ B[K,N] + bias[N]); row-major. BM=128,BN=64,BK=16.
__global__ __launch_bounds__(256) void gemm_f32(
    const float* __restrict__ A, const float* __restrict__ B,
    const float* __restrict__ bias, float* __restrict__ C,
    int M, int N, int K, int ldc, int act)
{
    __shared__ float As[16][132];
    __shared__ float Bs[16][68];
    const int tid = threadIdx.x;
    const int m0 = blockIdx.y * 128;
    const int n0 = blockIdx.x * 64;
    const int ak = tid & 15, am = tid >> 4;
    const int bn = tid & 63, bk = tid >> 6;
    const int tx = tid & 15, ty = tid >> 4;
    float acc[8][4] = {};
    for (int k0 = 0; k0 < K; k0 += 16) {
#pragma unroll
        for (int r = 0; r < 8; ++r)
            As[ak][am + 16 * r] = A[(size_t)(m0 + am + 16 * r) * K + k0 + ak];
#pragma unroll
        for (int r = 0; r < 4; ++r)
            Bs[bk + 4 * r][bn] = B[(size_t)(k0 + bk + 4 * r) * N + n0 + bn];
        __syncthreads();
#pragma unroll
        for (int k = 0; k < 16; ++k) {
            float4 a0 = *(const float4*)&As[k][ty * 8];
            float4 a1 = *(const float4*)&As[k][ty * 8 + 4];
            float4 b0 = *(const float4*)&Bs[k][tx * 4];
            float a[8] = {a0.x, a0.y, a0.z, a0.w, a1.x, a1.y, a1.z, a1.w};
            float b[4] = {b0.x, b0.y, b0.z, b0.w};
#pragma unroll
            for (int i = 0; i < 8; ++i)
#pragma unroll
                for (int j = 0; j < 4; ++j)
                    acc[i][j] = fmaf(a[i], b[j], acc[i][j]);
        }
        __syncthreads();
    }
#pragma unroll
    for (int i = 0; i < 8; ++i) {
        const int m = m0 + ty * 8 + i;
#pragma unroll
        for (int j = 0; j < 4; ++j) {
            const int n = n0 + tx * 4 + j;
            float v = acc[i][j] + bias[n];
            if (act) v = fmaxf(v, 0.f);
            C[(size_t)m * ldc + n] = v;
        }
    }
}

// Sequential GRU scan, one workgroup of 512 threads (8 waves, 2/SIMD).
// Quad layout: tid = i*4+g; g=0:r, g=1:z, g=2:n (g=3 dup).
// f16 weights packed 2/reg (64 VGPRs/thread), matvec via v_dot2_f32_f16.
// KEY (round 7): amdgpu_waves_per_eu(2,2) — rounds 3-6 showed the scheduler
// targets MAX occupancy (VGPR_Count pinned to 64/84) and spills the weight
// array to scratch, refetching every step (= the entire bottleneck).
// Setting max waves/EU = 2 makes 256 VGPRs free, so w2[64] stays resident.
__global__ __launch_bounds__(512)
__attribute__((amdgpu_waves_per_eu(2, 2)))
void gru_scan(
    const float* __restrict__ GI, const float* __restrict__ Whh,
    const float* __restrict__ bhh, const float* __restrict__ h0,
    double* __restrict__ esum_out, float* __restrict__ hfinal_out,
    float* __restrict__ D_out, int T)
{
    __shared__ unsigned short h16[2][HDIM];   // f16 state, double-buffered
    const int tid = threadIdx.x;
    const int i = tid >> 2;
    const int g = tid & 3;
    const int col = (g < 3 ? g : 2) * HDIM + i;   // PyTorch gate order r|z|n
    unsigned int w2[64];                           // 128 f16 weights, packed
#pragma unroll
    for (int p = 0; p < 64; ++p) {
        const _Float16 lo = (_Float16)Whh[(size_t)(2 * p)     * G3 + col];
        const _Float16 hi = (_Float16)Whh[(size_t)(2 * p + 1) * G3 + col];
        w2[p] = (unsigned int)__builtin_bit_cast(unsigned short, lo)
              | ((unsigned int)__builtin_bit_cast(unsigned short, hi) << 16);
    }
#pragma unroll
    for (int p = 0; p < 64; ++p) asm volatile("" : "+v"(w2[p]));  // pin live
    const float bh = bhh[col];
    if (tid < HDIM)
        h16[0][tid] = __builtin_bit_cast(unsigned short,
                                         (_Float16)(h0 ? h0[tid] : 0.f));
    double esum = 0.0;
    float gi_cur = GI[col];
    __syncthreads();
    for (int t = 0; t < T; ++t) {
        const float gi_nxt = GI[(size_t)(t + 1) * G3 + col];  // padded row ok
        const uint4* hb = (const uint4*)h16[t & 1];
        float a0 = 0.f, a1 = 0.f, a2 = 0.f, a3 = 0.f;
#pragma unroll
        for (int q = 0; q < 16; ++q) {
            const uint4 u = hb[q];   // wave-uniform addr: LDS broadcast, 8 f16
            a0 = fdot2(u.x, w2[4 * q + 0], a0);
            a1 = fdot2(u.y, w2[4 * q + 1], a1);
            a2 = fdot2(u.z, w2[4 * q + 2], a2);
            a3 = fdot2(u.w, w2[4 * q + 3], a3);
        }
        const float gh = (a0 + a1) + (a2 + a3) + bh;
        const float hp = (float)__builtin_bit_cast(_Float16, h16[t & 1][i]);
        const float s = sigm_fast(gi_cur + gh);
        const float r = bcast_q0(s);              // r gate from quad lane 0
        const float z = bcast_q1(s);              // z gate from quad lane 1
        const float n = tanh_fast(gi_cur + r * gh);
        const float hn = z * (hp - n) + n;        // (1-z)*n + z*hp
        if (g == 2) {
            h16[(t + 1) & 1][i] = __builtin_bit_cast(unsigned short, (_Float16)hn);
            esum += (double)hn;
            if (D_out) D_out[(size_t)t * HDIM + i] = hn;
        }
        gi_cur = gi_nxt;
        __syncthreads();  // single barrier/step: dbuf covers both hazards
    }
    if (g == 2) {
        if (esum_out) esum_out[i] = esum;
        if (hfinal_out)
            hfinal_out[i] = (float)__builtin_bit_cast(_Float16, h16[T & 1][i]);
    }
}

// c2[j] = b_comb[j] + sum_k esum[k] * W_comb[128+k][j]
__global__ void prep_dec(const double* __restrict__ esum, const float* __restrict__ W_comb,
                         const float* __restrict__ b_comb, float* __restrict__ c2)
{
    __shared__ double es[HDIM];
    const int j = threadIdx.x;
    es[j] = esum[j];
    __syncthreads();
    double acc = (double)b_comb[j];
    for (int k = 0; k < HDIM; ++k)
        acc += es[k] * (double)W_comb[(HDIM + k) * HDIM + j];
    c2[j] = (float)acc;
}

__global__ __launch_bounds__(256) void out_row(
    const float* __restrict__ D, const float* __restrict__ Wout,
    const float* __restrict__ b_out, float* __restrict__ out)
{
    const int row = (blockIdx.x * 256 + threadIdx.x) >> 6;
    const int lane = threadIdx.x & 63;
    float v = D[(size_t)row * HDIM + lane] * Wout[lane]
            + D[(size_t)row * HDIM + 64 + lane] * Wout[64 + lane];
#pragma unroll
    for (int s = 32; s > 0; s >>= 1) v += __shfl_down(v, s);
    if (lane == 0) out[row] = sigm(v + b_out[0]);
}

__global__ void copy_lw(const float* __restrict__ lab, const float* __restrict__ wt,
                        float* __restrict__ out)
{
    const int i = blockIdx.x * 256 + threadIdx.x;
    if (i < NBOX) { out[NBOX + i] = lab[i]; out[2 * NBOX + i] = wt[i]; }
}

extern "C" void kernel_launch(void* const* d_in, const int* in_sizes, int n_in,
                              void* d_out, int out_size, void* d_ws, size_t ws_size,
                              hipStream_t stream)
{
    const float* boxes_feature = (const float*)d_in[0];
    const float* boxes_score   = (const float*)d_in[1];
    const float* boxes_box     = (const float*)d_in[2];
    const float* boxes_label   = (const float*)d_in[3];
    const float* boxes_weight  = (const float*)d_in[4];
    const float* W_appear = (const float*)d_in[6];
    const float* b_appear = (const float*)d_in[7];
    const float* W_s1     = (const float*)d_in[8];
    const float* b_s1     = (const float*)d_in[9];
    const float* W_s2     = (const float*)d_in[10];
    const float* b_s2     = (const float*)d_in[11];
    const float* W_box    = (const float*)d_in[12];
    const float* b_box    = (const float*)d_in[13];
    const float* W_all    = (const float*)d_in[14];
    const float* b_all    = (const float*)d_in[15];
    const float* enc_Wih  = (const float*)d_in[16];
    const float* enc_Whh  = (const float*)d_in[17];
    const float* enc_bih  = (const float*)d_in[18];
    const float* enc_bhh  = (const float*)d_in[19];
    const float* dec_Wih  = (const float*)d_in[20];
    const float* dec_Whh  = (const float*)d_in[21];
    const float* dec_bih  = (const float*)d_in[22];
    const float* dec_bhh  = (const float*)d_in[23];
    // d_in[24] W_attn, d_in[25] b_attn: no effect (softmax over singleton)
    const float* W_comb   = (const float*)d_in[26];
    const float* b_comb   = (const float*)d_in[27];
    const float* W_out    = (const float*)d_in[28];
    const float* b_out    = (const float*)d_in[29];

    float* out = (float*)d_out;
    float* ws = (float*)d_ws;
    size_t o = 0;
    float* T1   = ws + o; o += (size_t)NBOX * 512;      // score@W_s1+b (LINEAR)
    float* XCAT = ws + o; o += (size_t)NBOX * G3;
    float* X    = ws + o; o += (size_t)NBOX * HDIM;
    float* GIE  = ws + o; o += (size_t)(NBOX + 1) * G3;
    float* GID  = ws + o; o += (size_t)(NBOX + 1) * G3;
    float* DIN  = ws + o; o += (size_t)NBOX * HDIM;
    float* D    = ws + o; o += (size_t)NBOX * HDIM;
    o = (o + 1) & ~(size_t)1;
    double* esum = (double*)(ws + o); o += 256;
    float* henc = ws + o; o += 128;
    float* c2   = ws + o; o += 128;

    // ---- phase 1: parallel feature GEMMs ----
    gemm_f32<<<dim3(512 / 64, NBOX / 128), 256, 0, stream>>>(
        boxes_score, W_s1, b_s1, T1, NBOX, 512, 2560, 512, 0);
    gemm_f32<<<dim3(HDIM / 64, NBOX / 128), 256, 0, stream>>>(
        boxes_feature, W_appear, b_appear, XCAT + 0, NBOX, HDIM, 1024, G3, 1);
    gemm_f32<<<dim3(HDIM / 64, NBOX / 128), 256, 0, stream>>>(
        T1, W_s2, b_s2, XCAT + HDIM, NBOX, HDIM, 512, G3, 1);
    gemm_f32<<<dim3(HDIM / 64, NBOX / 128), 256, 0, stream>>>(
        boxes_box, W_box, b_box, XCAT + 2 * HDIM, NBOX, HDIM, 320, G3, 1);
    gemm_f32<<<dim3(HDIM / 64, NBOX / 128), 256, 0, stream>>>(
        XCAT, W_all, b_all, X, NBOX, HDIM, G3, HDIM, 1);

    // ---- encoder ----
    gemm_f32<<<dim3(G3 / 64, NBOX / 128), 256, 0, stream>>>(
        X, enc_Wih, enc_bih, GIE, NBOX, G3, HDIM, G3, 0);
    gru_scan<<<1, 512, 0, stream>>>(GIE, enc_Whh, enc_bhh, nullptr,
                                    esum, henc, nullptr, NBOX);

    // ---- decoder prep (applied = esum constant across steps) ----
    prep_dec<<<1, 128, 0, stream>>>(esum, W_comb, b_comb, c2);
    gemm_f32<<<dim3(HDIM / 64, NBOX / 128), 256, 0, stream>>>(
        X, W_comb, c2, DIN, NBOX, HDIM, HDIM, HDIM, 1);
    gemm_f32<<<dim3(G3 / 64, NBOX / 128), 256, 0, stream>>>(
        DIN, dec_Wih, dec_bih, GID, NBOX, G3, HDIM, G3, 0);

    // ---- decoder scan ----
    gru_scan<<<1, 512, 0, stream>>>(GID, dec_Whh, dec_bhh, henc,
                                    nullptr, nullptr, D, NBOX);

    // ---- epilogue ----
    out_row<<<NBOX / 4, 256, 0, stream>>>(D, W_out, b_out, out);
    copy_lw<<<NBOX / 256, 256, 0, stream>>>(boxes_label, boxes_weight, out);
}

// Round 8
// 4675.325 us; speedup vs baseline: 1.1134x; 1.1134x over previous
//
#include <hip/hip_runtime.h>
#include <hip/hip_bf16.h>
#include <math.h>

#define NBOX 4096
#define HDIM 128
#define G3   384   // 3*H

typedef _Float16 half2v __attribute__((ext_vector_type(2)));

__device__ __forceinline__ float sigm(float x) { return 1.f / (1.f + expf(-x)); }
__device__ __forceinline__ float sigm_fast(float x) {
    return __builtin_amdgcn_rcpf(1.f + __expf(-x));
}
__device__ __forceinline__ float tanh_fast(float x) {
    x = fminf(15.f, fmaxf(-15.f, x));
    const float e2 = __expf(2.f * x);
    return (e2 - 1.f) * __builtin_amdgcn_rcpf(e2 + 1.f);
}
// DPP quad-perm broadcasts: quad lane k -> all 4 lanes of the quad
__device__ __forceinline__ float bcast_q0(float x) {
    return __int_as_float(__builtin_amdgcn_mov_dpp(__float_as_int(x), 0x00, 0xF, 0xF, false));
}
__device__ __forceinline__ float bcast_q1(float x) {
    return __int_as_float(__builtin_amdgcn_mov_dpp(__float_as_int(x), 0x55, 0xF, 0xF, false));
}
// quad all-reduce sum: butterfly over quad_perm [1,0,3,2] then [2,3,0,1]
__device__ __forceinline__ float qsum(float v) {
    v += __int_as_float(__builtin_amdgcn_mov_dpp(__float_as_int(v), 0xB1, 0xF, 0xF, false));
    v += __int_as_float(__builtin_amdgcn_mov_dpp(__float_as_int(v), 0x4E, 0xF, 0xF, false));
    return v;
}
// v_dot2_f32_f16: exact f16 products, f32 accumulate
__device__ __forceinline__ float fdot2(unsigned int h2, unsigned int w2, float acc) {
    return __builtin_amdgcn_fdot2(__builtin_bit_cast(half2v, h2),
                                  __builtin_bit_cast(half2v, w2), acc, false);
}

// C[M,N] = act(A[M,K] @ B[K,N] + bias[N]); row-major. BM=128,BN=64,BK=16.
__global__ __launch_bounds__(256) void gemm_f32(
    const float* __restrict__ A, const float* __restrict__ B,
    const float* __restrict__ bias, float* __restrict__ C,
    int M, int N, int K, int ldc, int act)
{
    __shared__ float As[16][132];
    __shared__ float Bs[16][68];
    const int tid = threadIdx.x;
    const int m0 = blockIdx.y * 128;
    const int n0 = blockIdx.x * 64;
    const int ak = tid & 15, am = tid >> 4;
    const int bn = tid & 63, bk = tid >> 6;
    const int tx = tid & 15, ty = tid >> 4;
    float acc[8][4] = {};
    for (int k0 = 0; k0 < K; k0 += 16) {
#pragma unroll
        for (int r = 0; r < 8; ++r)
            As[ak][am + 16 * r] = A[(size_t)(m0 + am + 16 * r) * K + k0 + ak];
#pragma unroll
        for (int r = 0; r < 4; ++r)
            Bs[bk + 4 * r][bn] = B[(size_t)(k0 + bk + 4 * r) * N + n0 + bn];
        __syncthreads();
#pragma unroll
        for (int k = 0; k < 16; ++k) {
            float4 a0 = *(const float4*)&As[k][ty * 8];
            float4 a1 = *(const float4*)&As[k][ty * 8 + 4];
            float4 b0 = *(const float4*)&Bs[k][tx * 4];
            float a[8] = {a0.x, a0.y, a0.z, a0.w, a1.x, a1.y, a1.z, a1.w};
            float b[4] = {b0.x, b0.y, b0.z, b0.w};
#pragma unroll
            for (int i = 0; i < 8; ++i)
#pragma unroll
                for (int j = 0; j < 4; ++j)
                    acc[i][j] = fmaf(a[i], b[j], acc[i][j]);
        }
        __syncthreads();
    }
#pragma unroll
    for (int i = 0; i < 8; ++i) {
        const int m = m0 + ty * 8 + i;
#pragma unroll
        for (int j = 0; j < 4; ++j) {
            const int n = n0 + tx * 4 + j;
            float v = acc[i][j] + bias[n];
            if (act) v = fmaxf(v, 0.f);
            C[(size_t)m * ldc + n] = v;
        }
    }
}

// Sequential GRU scan, 512 threads (8 waves, 2/SIMD).
// ROUND-8 STRUCTURE (quad-K-split): rounds 6/7 proved the bound is LDS
// return bandwidth — every thread read ALL 256B of h per step (~134KB/step
// /CU ~= 1500cyc at ~90B/cyc). Now quad q owns the (r,z,n) column triple
// for hidden index q; lane g of the quad covers k in [32g,32g+32) for all
// three columns (48 packed f16 weights in VGPRs). Each lane reads only its
// 64B h-quarter (4x ds_read_b128) -> 34KB/step/CU. Quarter-dots are
// combined by a 2-stage DPP quad butterfly; lane g then selects its gate
// and the round-6 epilogue (DPP r/z broadcast, 1 barrier, f64 esum) runs
// unchanged.
__global__ __launch_bounds__(512)
__attribute__((amdgpu_waves_per_eu(2, 2)))
void gru_scan(
    const float* __restrict__ GI, const float* __restrict__ Whh,
    const float* __restrict__ bhh, const float* __restrict__ h0,
    double* __restrict__ esum_out, float* __restrict__ hfinal_out,
    float* __restrict__ D_out, int T)
{
    __shared__ unsigned short h16[2][HDIM];   // f16 state, double-buffered
    const int tid = threadIdx.x;
    const int q = tid >> 2;                   // hidden index 0..127
    const int g = tid & 3;                    // k-quarter AND gate lane
    const int col = (g < 3 ? g : 2) * HDIM + q;   // gate col for gi/bias
    // weights: w2[c*16+j] = Whh[k..k+1][c*128+q], k = 32g+2j (f16 pair)
    unsigned int w2[48];
#pragma unroll
    for (int c = 0; c < 3; ++c)
#pragma unroll
        for (int j = 0; j < 16; ++j) {
            const int k = g * 32 + 2 * j;
            const int cc = c * HDIM + q;
            const _Float16 lo = (_Float16)Whh[(size_t)k * G3 + cc];
            const _Float16 hi = (_Float16)Whh[(size_t)(k + 1) * G3 + cc];
            w2[c * 16 + j] = (unsigned int)__builtin_bit_cast(unsigned short, lo)
                           | ((unsigned int)__builtin_bit_cast(unsigned short, hi) << 16);
        }
#pragma unroll
    for (int p = 0; p < 48; ++p) asm volatile("" : "+v"(w2[p]));  // keep live
    const float bh = bhh[col];
    if (tid < HDIM)
        h16[0][tid] = __builtin_bit_cast(unsigned short,
                                         (_Float16)(h0 ? h0[tid] : 0.f));
    double esum = 0.0;
    float gi_cur = GI[col];
    __syncthreads();
    for (int t = 0; t < T; ++t) {
        const float gi_nxt = GI[(size_t)(t + 1) * G3 + col];  // padded row ok
        const uint4* hb = (const uint4*)h16[t & 1];
        float a0 = 0.f, a1 = 0.f, a2 = 0.f;   // r, z, n quarter-dots
#pragma unroll
        for (int p = 0; p < 4; ++p) {
            const uint4 u = hb[4 * g + p];    // lane's own 16B of h
            a0 = fdot2(u.x, w2[4 * p + 0], a0);
            a0 = fdot2(u.y, w2[4 * p + 1], a0);
            a0 = fdot2(u.z, w2[4 * p + 2], a0);
            a0 = fdot2(u.w, w2[4 * p + 3], a0);
            a1 = fdot2(u.x, w2[16 + 4 * p + 0], a1);
            a1 = fdot2(u.y, w2[16 + 4 * p + 1], a1);
            a1 = fdot2(u.z, w2[16 + 4 * p + 2], a1);
            a1 = fdot2(u.w, w2[16 + 4 * p + 3], a1);
            a2 = fdot2(u.x, w2[32 + 4 * p + 0], a2);
            a2 = fdot2(u.y, w2[32 + 4 * p + 1], a2);
            a2 = fdot2(u.z, w2[32 + 4 * p + 2], a2);
            a2 = fdot2(u.w, w2[32 + 4 * p + 3], a2);
        }
        a0 = qsum(a0);                        // full r-sum in all quad lanes
        a1 = qsum(a1);                        // full z-sum
        a2 = qsum(a2);                        // full n-sum
        const float gh = ((g == 0) ? a0 : (g == 1) ? a1 : a2) + bh;
        const float hp = (float)__builtin_bit_cast(_Float16, h16[t & 1][q]);
        const float s = sigm_fast(gi_cur + gh);
        const float r = bcast_q0(s);          // r gate from quad lane 0
        const float z = bcast_q1(s);          // z gate from quad lane 1
        const float n = tanh_fast(gi_cur + r * gh);
        const float hn = z * (hp - n) + n;    // (1-z)*n + z*hp
        if (g == 2) {
            h16[(t + 1) & 1][q] = __builtin_bit_cast(unsigned short, (_Float16)hn);
            esum += (double)hn;
            if (D_out) D_out[(size_t)t * HDIM + q] = hn;
        }
        gi_cur = gi_nxt;
        __syncthreads();  // single barrier/step: dbuf covers both hazards
    }
    if (g == 2) {
        if (esum_out) esum_out[q] = esum;
        if (hfinal_out)
            hfinal_out[q] = (float)__builtin_bit_cast(_Float16, h16[T & 1][q]);
    }
}

// c2[j] = b_comb[j] + sum_k esum[k] * W_comb[128+k][j]
__global__ void prep_dec(const double* __restrict__ esum, const float* __restrict__ W_comb,
                         const float* __restrict__ b_comb, float* __restrict__ c2)
{
    __shared__ double es[HDIM];
    const int j = threadIdx.x;
    es[j] = esum[j];
    __syncthreads();
    double acc = (double)b_comb[j];
    for (int k = 0; k < HDIM; ++k)
        acc += es[k] * (double)W_comb[(HDIM + k) * HDIM + j];
    c2[j] = (float)acc;
}

__global__ __launch_bounds__(256) void out_row(
    const float* __restrict__ D, const float* __restrict__ Wout,
    const float* __restrict__ b_out, float* __restrict__ out)
{
    const int row = (blockIdx.x * 256 + threadIdx.x) >> 6;
    const int lane = threadIdx.x & 63;
    float v = D[(size_t)row * HDIM + lane] * Wout[lane]
            + D[(size_t)row * HDIM + 64 + lane] * Wout[64 + lane];
#pragma unroll
    for (int s = 32; s > 0; s >>= 1) v += __shfl_down(v, s);
    if (lane == 0) out[row] = sigm(v + b_out[0]);
}

__global__ void copy_lw(const float* __restrict__ lab, const float* __restrict__ wt,
                        float* __restrict__ out)
{
    const int i = blockIdx.x * 256 + threadIdx.x;
    if (i < NBOX) { out[NBOX + i] = lab[i]; out[2 * NBOX + i] = wt[i]; }
}

extern "C" void kernel_launch(void* const* d_in, const int* in_sizes, int n_in,
                              void* d_out, int out_size, void* d_ws, size_t ws_size,
                              hipStream_t stream)
{
    const float* boxes_feature = (const float*)d_in[0];
    const float* boxes_score   = (const float*)d_in[1];
    const float* boxes_box     = (const float*)d_in[2];
    const float* boxes_label   = (const float*)d_in[3];
    const float* boxes_weight  = (const float*)d_in[4];
    const float* W_appear = (const float*)d_in[6];
    const float* b_appear = (const float*)d_in[7];
    const float* W_s1     = (const float*)d_in[8];
    const float* b_s1     = (const float*)d_in[9];
    const float* W_s2     = (const float*)d_in[10];
    const float* b_s2     = (const float*)d_in[11];
    const float* W_box    = (const float*)d_in[12];
    const float* b_box    = (const float*)d_in[13];
    const float* W_all    = (const float*)d_in[14];
    const float* b_all    = (const float*)d_in[15];
    const float* enc_Wih  = (const float*)d_in[16];
    const float* enc_Whh  = (const float*)d_in[17];
    const float* enc_bih  = (const float*)d_in[18];
    const float* enc_bhh  = (const float*)d_in[19];
    const float* dec_Wih  = (const float*)d_in[20];
    const float* dec_Whh  = (const float*)d_in[21];
    const float* dec_bih  = (const float*)d_in[22];
    const float* dec_bhh  = (const float*)d_in[23];
    // d_in[24] W_attn, d_in[25] b_attn: no effect (softmax over singleton)
    const float* W_comb   = (const float*)d_in[26];
    const float* b_comb   = (const float*)d_in[27];
    const float* W_out    = (const float*)d_in[28];
    const float* b_out    = (const float*)d_in[29];

    float* out = (float*)d_out;
    float* ws = (float*)d_ws;
    size_t o = 0;
    float* T1   = ws + o; o += (size_t)NBOX * 512;      // score@W_s1+b (LINEAR)
    float* XCAT = ws + o; o += (size_t)NBOX * G3;
    float* X    = ws + o; o += (size_t)NBOX * HDIM;
    float* GIE  = ws + o; o += (size_t)(NBOX + 1) * G3;
    float* GID  = ws + o; o += (size_t)(NBOX + 1) * G3;
    float* DIN  = ws + o; o += (size_t)NBOX * HDIM;
    float* D    = ws + o; o += (size_t)NBOX * HDIM;
    o = (o + 1) & ~(size_t)1;
    double* esum = (double*)(ws + o); o += 256;
    float* henc = ws + o; o += 128;
    float* c2   = ws + o; o += 128;

    // ---- phase 1: parallel feature GEMMs ----
    gemm_f32<<<dim3(512 / 64, NBOX / 128), 256, 0, stream>>>(
        boxes_score, W_s1, b_s1, T1, NBOX, 512, 2560, 512, 0);
    gemm_f32<<<dim3(HDIM / 64, NBOX / 128), 256, 0, stream>>>(
        boxes_feature, W_appear, b_appear, XCAT + 0, NBOX, HDIM, 1024, G3, 1);
    gemm_f32<<<dim3(HDIM / 64, NBOX / 128), 256, 0, stream>>>(
        T1, W_s2, b_s2, XCAT + HDIM, NBOX, HDIM, 512, G3, 1);
    gemm_f32<<<dim3(HDIM / 64, NBOX / 128), 256, 0, stream>>>(
        boxes_box, W_box, b_box, XCAT + 2 * HDIM, NBOX, HDIM, 320, G3, 1);
    gemm_f32<<<dim3(HDIM / 64, NBOX / 128), 256, 0, stream>>>(
        XCAT, W_all, b_all, X, NBOX, HDIM, G3, HDIM, 1);

    // ---- encoder ----
    gemm_f32<<<dim3(G3 / 64, NBOX / 128), 256, 0, stream>>>(
        X, enc_Wih, enc_bih, GIE, NBOX, G3, HDIM, G3, 0);
    gru_scan<<<1, 512, 0, stream>>>(GIE, enc_Whh, enc_bhh, nullptr,
                                    esum, henc, nullptr, NBOX);

    // ---- decoder prep (applied = esum constant across steps) ----
    prep_dec<<<1, 128, 0, stream>>>(esum, W_comb, b_comb, c2);
    gemm_f32<<<dim3(HDIM / 64, NBOX / 128), 256, 0, stream>>>(
        X, W_comb, c2, DIN, NBOX, HDIM, HDIM, HDIM, 1);
    gemm_f32<<<dim3(G3 / 64, NBOX / 128), 256, 0, stream>>>(
        DIN, dec_Wih, dec_bih, GID, NBOX, G3, HDIM, G3, 0);

    // ---- decoder scan ----
    gru_scan<<<1, 512, 0, stream>>>(GID, dec_Whh, dec_bhh, henc,
                                    nullptr, nullptr, D, NBOX);

    // ---- epilogue ----
    out_row<<<NBOX / 4, 256, 0, stream>>>(D, W_out, b_out, out);
    copy_lw<<<NBOX / 256, 256, 0, stream>>>(boxes_label, boxes_weight, out);
}

// Round 9
// 4537.344 us; speedup vs baseline: 1.1473x; 1.0304x over previous
//
#include <hip/hip_runtime.h>
#include <hip/hip_bf16.h>
#include <math.h>

#define NBOX 4096
#define HDIM 128
#define G3   384   // 3*H
#define PF   8     // GI prefetch depth (steps)

typedef _Float16 half2v __attribute__((ext_vector_type(2)));

__device__ __forceinline__ float sigm(float x) { return 1.f / (1.f + expf(-x)); }
__device__ __forceinline__ float sigm_fast(float x) {
    return __builtin_amdgcn_rcpf(1.f + __expf(-x));
}
__device__ __forceinline__ float tanh_fast(float x) {
    x = fminf(15.f, fmaxf(-15.f, x));
    const float e2 = __expf(2.f * x);
    return (e2 - 1.f) * __builtin_amdgcn_rcpf(e2 + 1.f);
}
// DPP quad-perm broadcasts: quad lane k -> all 4 lanes of the quad
__device__ __forceinline__ float bcast_q0(float x) {
    return __int_as_float(__builtin_amdgcn_mov_dpp(__float_as_int(x), 0x00, 0xF, 0xF, false));
}
__device__ __forceinline__ float bcast_q1(float x) {
    return __int_as_float(__builtin_amdgcn_mov_dpp(__float_as_int(x), 0x55, 0xF, 0xF, false));
}
// quad all-reduce sum: butterfly over quad_perm [1,0,3,2] then [2,3,0,1]
__device__ __forceinline__ float qsum(float v) {
    v += __int_as_float(__builtin_amdgcn_mov_dpp(__float_as_int(v), 0xB1, 0xF, 0xF, false));
    v += __int_as_float(__builtin_amdgcn_mov_dpp(__float_as_int(v), 0x4E, 0xF, 0xF, false));
    return v;
}
// v_dot2_f32_f16: exact f16 products, f32 accumulate
__device__ __forceinline__ float fdot2(unsigned int h2, unsigned int w2, float acc) {
    return __builtin_amdgcn_fdot2(__builtin_bit_cast(half2v, h2),
                                  __builtin_bit_cast(half2v, w2), acc, false);
}
// LDS-only barrier: __syncthreads() emits s_waitcnt vmcnt(0) lgkmcnt(0) which
// DRAINS the in-flight GI prefetch / D_out store every step (~200-600cyc of
// L2/L3 latency on the critical path — the round-6..8 mystery gap). Only LDS
// ordering is a cross-wave hazard here, so wait lgkmcnt only.
__device__ __forceinline__ void bar_lds() {
    asm volatile("s_waitcnt lgkmcnt(0)\n\ts_barrier" ::: "memory");
}

// C[M,N] = act(A[M,K] @ B[K,N] + bias[N]); row-major. BM=128,BN=64,BK=16.
__global__ __launch_bounds__(256) void gemm_f32(
    const float* __restrict__ A, const float* __restrict__ B,
    const float* __restrict__ bias, float* __restrict__ C,
    int M, int N, int K, int ldc, int act)
{
    __shared__ float As[16][132];
    __shared__ float Bs[16][68];
    const int tid = threadIdx.x;
    const int m0 = blockIdx.y * 128;
    const int n0 = blockIdx.x * 64;
    const int ak = tid & 15, am = tid >> 4;
    const int bn = tid & 63, bk = tid >> 6;
    const int tx = tid & 15, ty = tid >> 4;
    float acc[8][4] = {};
    for (int k0 = 0; k0 < K; k0 += 16) {
#pragma unroll
        for (int r = 0; r < 8; ++r)
            As[ak][am + 16 * r] = A[(size_t)(m0 + am + 16 * r) * K + k0 + ak];
#pragma unroll
        for (int r = 0; r < 4; ++r)
            Bs[bk + 4 * r][bn] = B[(size_t)(k0 + bk + 4 * r) * N + n0 + bn];
        __syncthreads();
#pragma unroll
        for (int k = 0; k < 16; ++k) {
            float4 a0 = *(const float4*)&As[k][ty * 8];
            float4 a1 = *(const float4*)&As[k][ty * 8 + 4];
            float4 b0 = *(const float4*)&Bs[k][tx * 4];
            float a[8] = {a0.x, a0.y, a0.z, a0.w, a1.x, a1.y, a1.z, a1.w};
            float b[4] = {b0.x, b0.y, b0.z, b0.w};
#pragma unroll
            for (int i = 0; i < 8; ++i)
#pragma unroll
                for (int j = 0; j < 4; ++j)
                    acc[i][j] = fmaf(a[i], b[j], acc[i][j]);
        }
        __syncthreads();
    }
#pragma unroll
    for (int i = 0; i < 8; ++i) {
        const int m = m0 + ty * 8 + i;
#pragma unroll
        for (int j = 0; j < 4; ++j) {
            const int n = n0 + tx * 4 + j;
            float v = acc[i][j] + bias[n];
            if (act) v = fmaxf(v, 0.f);
            C[(size_t)m * ldc + n] = v;
        }
    }
}

// Sequential GRU scan, 512 threads (8 waves, 2/SIMD). Quad-K-split layout
// (round 8): quad q owns the (r,z,n) triple for hidden index q; lane g
// covers k in [32g,32g+32) (48 packed f16 weights, VGPR-resident). Round 9:
// raw lgkm-only barrier + PF-deep GI register prefetch so global latency is
// off the per-step critical path.
__global__ __launch_bounds__(512)
__attribute__((amdgpu_waves_per_eu(2, 2)))
void gru_scan(
    const float* __restrict__ GI, const float* __restrict__ Whh,
    const float* __restrict__ bhh, const float* __restrict__ h0,
    double* __restrict__ esum_out, float* __restrict__ hfinal_out,
    float* __restrict__ D_out, int T)
{
    __shared__ unsigned short h16[2][HDIM];   // f16 state, double-buffered
    const int tid = threadIdx.x;
    const int q = tid >> 2;                   // hidden index 0..127
    const int g = tid & 3;                    // k-quarter AND gate lane
    const int col = (g < 3 ? g : 2) * HDIM + q;   // gate col for gi/bias
    // weights: w2[c*16+j] = Whh[k..k+1][c*128+q], k = 32g+2j (f16 pair)
    unsigned int w2[48];
#pragma unroll
    for (int c = 0; c < 3; ++c)
#pragma unroll
        for (int j = 0; j < 16; ++j) {
            const int k = g * 32 + 2 * j;
            const int cc = c * HDIM + q;
            const _Float16 lo = (_Float16)Whh[(size_t)k * G3 + cc];
            const _Float16 hi = (_Float16)Whh[(size_t)(k + 1) * G3 + cc];
            w2[c * 16 + j] = (unsigned int)__builtin_bit_cast(unsigned short, lo)
                           | ((unsigned int)__builtin_bit_cast(unsigned short, hi) << 16);
        }
#pragma unroll
    for (int p = 0; p < 48; ++p) asm volatile("" : "+v"(w2[p]));  // keep live
    const float bh = bhh[col];
    if (tid < HDIM)
        h16[0][tid] = __builtin_bit_cast(unsigned short,
                                         (_Float16)(h0 ? h0[tid] : 0.f));
    double esum = 0.0;
    // GI prefetch: PF steps in registers, static-indexed double buffer.
    float gi_buf[PF], gi_nx[PF];
#pragma unroll
    for (int p = 0; p < PF; ++p) gi_buf[p] = GI[(size_t)p * G3 + col];
    __syncthreads();
    for (int t0 = 0; t0 < T; t0 += PF) {
        // issue next block's loads now; consumed PF steps later (latency hidden)
#pragma unroll
        for (int p = 0; p < PF; ++p)
            gi_nx[p] = GI[(size_t)(t0 + PF + p) * G3 + col];  // padded rows ok
#pragma unroll
        for (int p = 0; p < PF; ++p) {
            const int t = t0 + p;
            const float gi_cur = gi_buf[p];
            const uint4* hb = (const uint4*)h16[t & 1];
            float a0 = 0.f, a1 = 0.f, a2 = 0.f;   // r, z, n quarter-dots
#pragma unroll
            for (int pp = 0; pp < 4; ++pp) {
                const uint4 u = hb[4 * g + pp];   // lane's own 16B of h
                a0 = fdot2(u.x, w2[4 * pp + 0], a0);
                a0 = fdot2(u.y, w2[4 * pp + 1], a0);
                a0 = fdot2(u.z, w2[4 * pp + 2], a0);
                a0 = fdot2(u.w, w2[4 * pp + 3], a0);
                a1 = fdot2(u.x, w2[16 + 4 * pp + 0], a1);
                a1 = fdot2(u.y, w2[16 + 4 * pp + 1], a1);
                a1 = fdot2(u.z, w2[16 + 4 * pp + 2], a1);
                a1 = fdot2(u.w, w2[16 + 4 * pp + 3], a1);
                a2 = fdot2(u.x, w2[32 + 4 * pp + 0], a2);
                a2 = fdot2(u.y, w2[32 + 4 * pp + 1], a2);
                a2 = fdot2(u.z, w2[32 + 4 * pp + 2], a2);
                a2 = fdot2(u.w, w2[32 + 4 * pp + 3], a2);
            }
            a0 = qsum(a0);                    // full r-sum in all quad lanes
            a1 = qsum(a1);                    // full z-sum
            a2 = qsum(a2);                    // full n-sum
            const float gh = ((g == 0) ? a0 : (g == 1) ? a1 : a2) + bh;
            const float hp = (float)__builtin_bit_cast(_Float16, h16[t & 1][q]);
            const float s = sigm_fast(gi_cur + gh);
            const float r = bcast_q0(s);      // r gate from quad lane 0
            const float z = bcast_q1(s);      // z gate from quad lane 1
            const float n = tanh_fast(gi_cur + r * gh);
            const float hn = z * (hp - n) + n;    // (1-z)*n + z*hp
            if (g == 2) {
                h16[(t + 1) & 1][q] = __builtin_bit_cast(unsigned short, (_Float16)hn);
                esum += (double)hn;
                if (D_out) D_out[(size_t)t * HDIM + q] = hn;
            }
            bar_lds();   // LDS-only: global prefetch/stores stay in flight
        }
#pragma unroll
        for (int p = 0; p < PF; ++p) gi_buf[p] = gi_nx[p];  // waits vmem once/PF
    }
    if (g == 2) {
        if (esum_out) esum_out[q] = esum;
        if (hfinal_out)
            hfinal_out[q] = (float)__builtin_bit_cast(_Float16, h16[T & 1][q]);
    }
}

// c2[j] = b_comb[j] + sum_k esum[k] * W_comb[128+k][j]
__global__ void prep_dec(const double* __restrict__ esum, const float* __restrict__ W_comb,
                         const float* __restrict__ b_comb, float* __restrict__ c2)
{
    __shared__ double es[HDIM];
    const int j = threadIdx.x;
    es[j] = esum[j];
    __syncthreads();
    double acc = (double)b_comb[j];
    for (int k = 0; k < HDIM; ++k)
        acc += es[k] * (double)W_comb[(HDIM + k) * HDIM + j];
    c2[j] = (float)acc;
}

__global__ __launch_bounds__(256) void out_row(
    const float* __restrict__ D, const float* __restrict__ Wout,
    const float* __restrict__ b_out, float* __restrict__ out)
{
    const int row = (blockIdx.x * 256 + threadIdx.x) >> 6;
    const int lane = threadIdx.x & 63;
    float v = D[(size_t)row * HDIM + lane] * Wout[lane]
            + D[(size_t)row * HDIM + 64 + lane] * Wout[64 + lane];
#pragma unroll
    for (int s = 32; s > 0; s >>= 1) v += __shfl_down(v, s);
    if (lane == 0) out[row] = sigm(v + b_out[0]);
}

__global__ void copy_lw(const float* __restrict__ lab, const float* __restrict__ wt,
                        float* __restrict__ out)
{
    const int i = blockIdx.x * 256 + threadIdx.x;
    if (i < NBOX) { out[NBOX + i] = lab[i]; out[2 * NBOX + i] = wt[i]; }
}

extern "C" void kernel_launch(void* const* d_in, const int* in_sizes, int n_in,
                              void* d_out, int out_size, void* d_ws, size_t ws_size,
                              hipStream_t stream)
{
    const float* boxes_feature = (const float*)d_in[0];
    const float* boxes_score   = (const float*)d_in[1];
    const float* boxes_box     = (const float*)d_in[2];
    const float* boxes_label   = (const float*)d_in[3];
    const float* boxes_weight  = (const float*)d_in[4];
    const float* W_appear = (const float*)d_in[6];
    const float* b_appear = (const float*)d_in[7];
    const float* W_s1     = (const float*)d_in[8];
    const float* b_s1     = (const float*)d_in[9];
    const float* W_s2     = (const float*)d_in[10];
    const float* b_s2     = (const float*)d_in[11];
    const float* W_box    = (const float*)d_in[12];
    const float* b_box    = (const float*)d_in[13];
    const float* W_all    = (const float*)d_in[14];
    const float* b_all    = (const float*)d_in[15];
    const float* enc_Wih  = (const float*)d_in[16];
    const float* enc_Whh  = (const float*)d_in[17];
    const float* enc_bih  = (const float*)d_in[18];
    const float* enc_bhh  = (const float*)d_in[19];
    const float* dec_Wih  = (const float*)d_in[20];
    const float* dec_Whh  = (const float*)d_in[21];
    const float* dec_bih  = (const float*)d_in[22];
    const float* dec_bhh  = (const float*)d_in[23];
    // d_in[24] W_attn, d_in[25] b_attn: no effect (softmax over singleton)
    const float* W_comb   = (const float*)d_in[26];
    const float* b_comb   = (const float*)d_in[27];
    const float* W_out    = (const float*)d_in[28];
    const float* b_out    = (const float*)d_in[29];

    float* out = (float*)d_out;
    float* ws = (float*)d_ws;
    size_t o = 0;
    float* T1   = ws + o; o += (size_t)NBOX * 512;      // score@W_s1+b (LINEAR)
    float* XCAT = ws + o; o += (size_t)NBOX * G3;
    float* X    = ws + o; o += (size_t)NBOX * HDIM;
    float* GIE  = ws + o; o += (size_t)(NBOX + PF) * G3;  // padded for prefetch
    float* GID  = ws + o; o += (size_t)(NBOX + PF) * G3;
    float* DIN  = ws + o; o += (size_t)NBOX * HDIM;
    float* D    = ws + o; o += (size_t)NBOX * HDIM;
    o = (o + 1) & ~(size_t)1;
    double* esum = (double*)(ws + o); o += 256;
    float* henc = ws + o; o += 128;
    float* c2   = ws + o; o += 128;

    // ---- phase 1: parallel feature GEMMs ----
    gemm_f32<<<dim3(512 / 64, NBOX / 128), 256, 0, stream>>>(
        boxes_score, W_s1, b_s1, T1, NBOX, 512, 2560, 512, 0);
    gemm_f32<<<dim3(HDIM / 64, NBOX / 128), 256, 0, stream>>>(
        boxes_feature, W_appear, b_appear, XCAT + 0, NBOX, HDIM, 1024, G3, 1);
    gemm_f32<<<dim3(HDIM / 64, NBOX / 128), 256, 0, stream>>>(
        T1, W_s2, b_s2, XCAT + HDIM, NBOX, HDIM, 512, G3, 1);
    gemm_f32<<<dim3(HDIM / 64, NBOX / 128), 256, 0, stream>>>(
        boxes_box, W_box, b_box, XCAT + 2 * HDIM, NBOX, HDIM, 320, G3, 1);
    gemm_f32<<<dim3(HDIM / 64, NBOX / 128), 256, 0, stream>>>(
        XCAT, W_all, b_all, X, NBOX, HDIM, G3, HDIM, 1);

    // ---- encoder ----
    gemm_f32<<<dim3(G3 / 64, NBOX / 128), 256, 0, stream>>>(
        X, enc_Wih, enc_bih, GIE, NBOX, G3, HDIM, G3, 0);
    gru_scan<<<1, 512, 0, stream>>>(GIE, enc_Whh, enc_bhh, nullptr,
                                    esum, henc, nullptr, NBOX);

    // ---- decoder prep (applied = esum constant across steps) ----
    prep_dec<<<1, 128, 0, stream>>>(esum, W_comb, b_comb, c2);
    gemm_f32<<<dim3(HDIM / 64, NBOX / 128), 256, 0, stream>>>(
        X, W_comb, c2, DIN, NBOX, HDIM, HDIM, HDIM, 1);
    gemm_f32<<<dim3(G3 / 64, NBOX / 128), 256, 0, stream>>>(
        DIN, dec_Wih, dec_bih, GID, NBOX, G3, HDIM, G3, 0);

    // ---- decoder scan ----
    gru_scan<<<1, 512, 0, stream>>>(GID, dec_Whh, dec_bhh, henc,
                                    nullptr, nullptr, D, NBOX);

    // ---- epilogue ----
    out_row<<<NBOX / 4, 256, 0, stream>>>(D, W_out, b_out, out);
    copy_lw<<<NBOX / 256, 256, 0, stream>>>(boxes_label, boxes_weight, out);
}

// Round 10
// 4127.071 us; speedup vs baseline: 1.2613x; 1.0994x over previous
//
#include <hip/hip_runtime.h>
#include <hip/hip_bf16.h>
#include <math.h>

#define NBOX 4096
#define HDIM 128
#define G3   384   // 3*H
#define PF   8     // GI prefetch depth (steps)

typedef _Float16 half2v __attribute__((ext_vector_type(2)));

__device__ __forceinline__ float sigm(float x) { return 1.f / (1.f + expf(-x)); }
__device__ __forceinline__ float sigm_fast(float x) {
    return __builtin_amdgcn_rcpf(1.f + __expf(-x));
}
__device__ __forceinline__ float tanh_fast(float x) {
    x = fminf(15.f, fmaxf(-15.f, x));
    const float e2 = __expf(2.f * x);
    return (e2 - 1.f) * __builtin_amdgcn_rcpf(e2 + 1.f);
}
// DPP quad-perm broadcasts: quad lane k -> all 4 lanes of the quad
__device__ __forceinline__ float bcast_q1(float x) {
    return __int_as_float(__builtin_amdgcn_mov_dpp(__float_as_int(x), 0x55, 0xF, 0xF, false));
}
__device__ __forceinline__ float bcast_q3(float x) {
    return __int_as_float(__builtin_amdgcn_mov_dpp(__float_as_int(x), 0xFF, 0xF, 0xF, false));
}
// quad all-reduce sum: butterfly over quad_perm [1,0,3,2] then [2,3,0,1]
__device__ __forceinline__ float qsum(float v) {
    v += __int_as_float(__builtin_amdgcn_mov_dpp(__float_as_int(v), 0xB1, 0xF, 0xF, false));
    v += __int_as_float(__builtin_amdgcn_mov_dpp(__float_as_int(v), 0x4E, 0xF, 0xF, false));
    return v;
}
// v_dot2_f32_f16: exact f16 products, f32 accumulate
__device__ __forceinline__ float fdot2(unsigned int h2, unsigned int w2, float acc) {
    return __builtin_amdgcn_fdot2(__builtin_bit_cast(half2v, h2),
                                  __builtin_bit_cast(half2v, w2), acc, false);
}
// LDS-only barrier: keeps global prefetch/stores in flight (no vmcnt drain)
__device__ __forceinline__ void bar_lds() {
    asm volatile("s_waitcnt lgkmcnt(0)\n\ts_barrier" ::: "memory");
}

// C[M,N] = act(A[M,K] @ B[K,N] + bias[N]); row-major. BM=128,BN=64,BK=16.
__global__ __launch_bounds__(256) void gemm_f32(
    const float* __restrict__ A, const float* __restrict__ B,
    const float* __restrict__ bias, float* __restrict__ C,
    int M, int N, int K, int ldc, int act)
{
    __shared__ float As[16][132];
    __shared__ float Bs[16][68];
    const int tid = threadIdx.x;
    const int m0 = blockIdx.y * 128;
    const int n0 = blockIdx.x * 64;
    const int ak = tid & 15, am = tid >> 4;
    const int bn = tid & 63, bk = tid >> 6;
    const int tx = tid & 15, ty = tid >> 4;
    float acc[8][4] = {};
    for (int k0 = 0; k0 < K; k0 += 16) {
#pragma unroll
        for (int r = 0; r < 8; ++r)
            As[ak][am + 16 * r] = A[(size_t)(m0 + am + 16 * r) * K + k0 + ak];
#pragma unroll
        for (int r = 0; r < 4; ++r)
            Bs[bk + 4 * r][bn] = B[(size_t)(k0 + bk + 4 * r) * N + n0 + bn];
        __syncthreads();
#pragma unroll
        for (int k = 0; k < 16; ++k) {
            float4 a0 = *(const float4*)&As[k][ty * 8];
            float4 a1 = *(const float4*)&As[k][ty * 8 + 4];
            float4 b0 = *(const float4*)&Bs[k][tx * 4];
            float a[8] = {a0.x, a0.y, a0.z, a0.w, a1.x, a1.y, a1.z, a1.w};
            float b[4] = {b0.x, b0.y, b0.z, b0.w};
#pragma unroll
            for (int i = 0; i < 8; ++i)
#pragma unroll
                for (int j = 0; j < 4; ++j)
                    acc[i][j] = fmaf(a[i], b[j], acc[i][j]);
        }
        __syncthreads();
    }
#pragma unroll
    for (int i = 0; i < 8; ++i) {
        const int m = m0 + ty * 8 + i;
#pragma unroll
        for (int j = 0; j < 4; ++j) {
            const int n = n0 + tx * 4 + j;
            float v = acc[i][j] + bias[n];
            if (act) v = fmaxf(v, 0.f);
            C[(size_t)m * ldc + n] = v;
        }
    }
}

// Sequential GRU scan, ROUND-10 STRUCTURE: 256 threads (4 waves, 1/SIMD).
// Round-9 analysis: step time = dependence chain (~460cy) + LDS-pipe
// serialization (8 waves x 6 LDS instrs x ~10cy ~= 480cy). Fix: halve the
// wave count (LDS instrs/step 48 -> 20) and delete the hp ds_read via
// register carry. Quad j owns hidden pair (2j, 2j+1): 6 gate columns.
// Lane g: k-quarter [32g,32g+32) for all 6 cols (96 packed-f16 VGPRs,
// 96 dot2/step). Lane roles: g=0:sig_r(a)+tanh_n(a), g=1:sig_z(a),
// g=2:sig_r(b)+tanh_n(b), g=3:sig_z(b). r is LOCAL to the tanh lane (no
// bcast on the r->tanh chain); z arrives via 2 quad-perm bcasts.
__global__ __launch_bounds__(256)
__attribute__((amdgpu_waves_per_eu(1, 1)))
void gru_scan(
    const float* __restrict__ GI, const float* __restrict__ Whh,
    const float* __restrict__ bhh, const float* __restrict__ h0,
    double* __restrict__ esum_out, float* __restrict__ hfinal_out,
    float* __restrict__ D_out, int T)
{
    __shared__ unsigned short h16[2][HDIM];   // f16 state, double-buffered
    const int tid = threadIdx.x;              // 0..255
    const int j = tid >> 2;                   // quad 0..63
    const int g = tid & 3;
    const int qa = 2 * j, qb = 2 * j + 1;
    const int myq = (g & 2) ? qb : qa;
    const int colS = ((g & 1) ? HDIM : 0) + myq;  // this lane's sigmoid col
    const int colT = 2 * HDIM + myq;              // this lane's tanh col
    // weights: w[c6*16 + p2] = Whh[k..k+1][col(c6)], k = 32g + 2*p2
    // c6: 0=r(a) 1=z(a) 2=n(a) 3=r(b) 4=z(b) 5=n(b)
    unsigned int w[96];
#pragma unroll
    for (int c6 = 0; c6 < 6; ++c6) {
        const int cc = (c6 % 3) * HDIM + ((c6 < 3) ? qa : qb);
#pragma unroll
        for (int p2 = 0; p2 < 16; ++p2) {
            const int k = 32 * g + 2 * p2;
            const _Float16 lo = (_Float16)Whh[(size_t)k * G3 + cc];
            const _Float16 hi = (_Float16)Whh[(size_t)(k + 1) * G3 + cc];
            w[c6 * 16 + p2] = (unsigned int)__builtin_bit_cast(unsigned short, lo)
                            | ((unsigned int)__builtin_bit_cast(unsigned short, hi) << 16);
        }
    }
#pragma unroll
    for (int p = 0; p < 96; ++p) asm volatile("" : "+v"(w[p]));  // keep live
    const float bS = bhh[colS];
    const float bT = bhh[colT];
    if (tid < HDIM)
        h16[0][tid] = __builtin_bit_cast(unsigned short,
                                         (_Float16)(h0 ? h0[tid] : 0.f));
    // register-carried previous-h (f16-rounded, matching the LDS copy)
    float hp = (float)(_Float16)(h0 ? h0[myq] : 0.f);
    double esum = 0.0;
    // GI prefetch: PF steps of (sigmoid-col, tanh-col) pairs in registers
    float gS[PF], gT[PF], gSn[PF], gTn[PF];
#pragma unroll
    for (int p = 0; p < PF; ++p) {
        gS[p] = GI[(size_t)p * G3 + colS];
        gT[p] = GI[(size_t)p * G3 + colT];
    }
    __syncthreads();
    for (int t0 = 0; t0 < T; t0 += PF) {
#pragma unroll
        for (int p = 0; p < PF; ++p) {   // issue next block early (hidden)
            gSn[p] = GI[(size_t)(t0 + PF + p) * G3 + colS];
            gTn[p] = GI[(size_t)(t0 + PF + p) * G3 + colT];
        }
#pragma unroll
        for (int p = 0; p < PF; ++p) {
            const int t = t0 + p;
            const uint4* hb = (const uint4*)h16[t & 1];
            uint4 uu[4];
#pragma unroll
            for (int pp = 0; pp < 4; ++pp) uu[pp] = hb[4 * g + pp];
            float s0 = 0.f, s1 = 0.f, s2 = 0.f, s3 = 0.f, s4 = 0.f, s5 = 0.f;
#pragma unroll
            for (int pp = 0; pp < 4; ++pp) {
                const unsigned int x[4] = {uu[pp].x, uu[pp].y, uu[pp].z, uu[pp].w};
#pragma unroll
                for (int i2 = 0; i2 < 4; ++i2) {
                    const int pi = 4 * pp + i2;
                    s0 = fdot2(x[i2], w[pi], s0);
                    s1 = fdot2(x[i2], w[16 + pi], s1);
                    s2 = fdot2(x[i2], w[32 + pi], s2);
                    s3 = fdot2(x[i2], w[48 + pi], s3);
                    s4 = fdot2(x[i2], w[64 + pi], s4);
                    s5 = fdot2(x[i2], w[80 + pi], s5);
                }
            }
            s0 = qsum(s0); s1 = qsum(s1); s2 = qsum(s2);
            s3 = qsum(s3); s4 = qsum(s4); s5 = qsum(s5);
            // per-lane gate selection (all lanes hold all 6 sums)
            const float ghS = ((g & 2) ? ((g & 1) ? s4 : s3)
                                       : ((g & 1) ? s1 : s0)) + bS;
            const float ghT = ((g & 2) ? s5 : s2) + bT;
            const float s = sigm_fast(gS[p] + ghS);       // lane's sigmoid gate
            const float n = tanh_fast(gT[p] + s * ghT);   // r is local (g=0,2)
            const float z1 = bcast_q1(s);                 // z(a) from lane 1
            const float z3 = bcast_q3(s);                 // z(b) from lane 3
            const float z = (g & 2) ? z3 : z1;
            const float hn = z * (hp - n) + n;            // (1-z)*n + z*hp
            if (!(g & 1)) {                               // lanes 0,2 own hn
                h16[(t + 1) & 1][myq] =
                    __builtin_bit_cast(unsigned short, (_Float16)hn);
                esum += (double)hn;
                if (D_out) D_out[(size_t)t * HDIM + myq] = hn;
            }
            hp = (float)(_Float16)hn;                     // register carry
            bar_lds();   // LDS-only barrier: globals stay in flight
        }
#pragma unroll
        for (int p = 0; p < PF; ++p) { gS[p] = gSn[p]; gT[p] = gTn[p]; }
    }
    if (!(g & 1)) {
        if (esum_out) esum_out[myq] = esum;
        if (hfinal_out) hfinal_out[myq] = hp;
    }
}

// c2[j] = b_comb[j] + sum_k esum[k] * W_comb[128+k][j]
__global__ void prep_dec(const double* __restrict__ esum, const float* __restrict__ W_comb,
                         const float* __restrict__ b_comb, float* __restrict__ c2)
{
    __shared__ double es[HDIM];
    const int j = threadIdx.x;
    es[j] = esum[j];
    __syncthreads();
    double acc = (double)b_comb[j];
    for (int k = 0; k < HDIM; ++k)
        acc += es[k] * (double)W_comb[(HDIM + k) * HDIM + j];
    c2[j] = (float)acc;
}

__global__ __launch_bounds__(256) void out_row(
    const float* __restrict__ D, const float* __restrict__ Wout,
    const float* __restrict__ b_out, float* __restrict__ out)
{
    const int row = (blockIdx.x * 256 + threadIdx.x) >> 6;
    const int lane = threadIdx.x & 63;
    float v = D[(size_t)row * HDIM + lane] * Wout[lane]
            + D[(size_t)row * HDIM + 64 + lane] * Wout[64 + lane];
#pragma unroll
    for (int s = 32; s > 0; s >>= 1) v += __shfl_down(v, s);
    if (lane == 0) out[row] = sigm(v + b_out[0]);
}

__global__ void copy_lw(const float* __restrict__ lab, const float* __restrict__ wt,
                        float* __restrict__ out)
{
    const int i = blockIdx.x * 256 + threadIdx.x;
    if (i < NBOX) { out[NBOX + i] = lab[i]; out[2 * NBOX + i] = wt[i]; }
}

extern "C" void kernel_launch(void* const* d_in, const int* in_sizes, int n_in,
                              void* d_out, int out_size, void* d_ws, size_t ws_size,
                              hipStream_t stream)
{
    const float* boxes_feature = (const float*)d_in[0];
    const float* boxes_score   = (const float*)d_in[1];
    const float* boxes_box     = (const float*)d_in[2];
    const float* boxes_label   = (const float*)d_in[3];
    const float* boxes_weight  = (const float*)d_in[4];
    const float* W_appear = (const float*)d_in[6];
    const float* b_appear = (const float*)d_in[7];
    const float* W_s1     = (const float*)d_in[8];
    const float* b_s1     = (const float*)d_in[9];
    const float* W_s2     = (const float*)d_in[10];
    const float* b_s2     = (const float*)d_in[11];
    const float* W_box    = (const float*)d_in[12];
    const float* b_box    = (const float*)d_in[13];
    const float* W_all    = (const float*)d_in[14];
    const float* b_all    = (const float*)d_in[15];
    const float* enc_Wih  = (const float*)d_in[16];
    const float* enc_Whh  = (const float*)d_in[17];
    const float* enc_bih  = (const float*)d_in[18];
    const float* enc_bhh  = (const float*)d_in[19];
    const float* dec_Wih  = (const float*)d_in[20];
    const float* dec_Whh  = (const float*)d_in[21];
    const float* dec_bih  = (const float*)d_in[22];
    const float* dec_bhh  = (const float*)d_in[23];
    // d_in[24] W_attn, d_in[25] b_attn: no effect (softmax over singleton)
    const float* W_comb   = (const float*)d_in[26];
    const float* b_comb   = (const float*)d_in[27];
    const float* W_out    = (const float*)d_in[28];
    const float* b_out    = (const float*)d_in[29];

    float* out = (float*)d_out;
    float* ws = (float*)d_ws;
    size_t o = 0;
    float* T1   = ws + o; o += (size_t)NBOX * 512;      // score@W_s1+b (LINEAR)
    float* XCAT = ws + o; o += (size_t)NBOX * G3;
    float* X    = ws + o; o += (size_t)NBOX * HDIM;
    float* GIE  = ws + o; o += (size_t)(NBOX + PF) * G3;  // padded for prefetch
    float* GID  = ws + o; o += (size_t)(NBOX + PF) * G3;
    float* DIN  = ws + o; o += (size_t)NBOX * HDIM;
    float* D    = ws + o; o += (size_t)NBOX * HDIM;
    o = (o + 1) & ~(size_t)1;
    double* esum = (double*)(ws + o); o += 256;
    float* henc = ws + o; o += 128;
    float* c2   = ws + o; o += 128;

    // ---- phase 1: parallel feature GEMMs ----
    gemm_f32<<<dim3(512 / 64, NBOX / 128), 256, 0, stream>>>(
        boxes_score, W_s1, b_s1, T1, NBOX, 512, 2560, 512, 0);
    gemm_f32<<<dim3(HDIM / 64, NBOX / 128), 256, 0, stream>>>(
        boxes_feature, W_appear, b_appear, XCAT + 0, NBOX, HDIM, 1024, G3, 1);
    gemm_f32<<<dim3(HDIM / 64, NBOX / 128), 256, 0, stream>>>(
        T1, W_s2, b_s2, XCAT + HDIM, NBOX, HDIM, 512, G3, 1);
    gemm_f32<<<dim3(HDIM / 64, NBOX / 128), 256, 0, stream>>>(
        boxes_box, W_box, b_box, XCAT + 2 * HDIM, NBOX, HDIM, 320, G3, 1);
    gemm_f32<<<dim3(HDIM / 64, NBOX / 128), 256, 0, stream>>>(
        XCAT, W_all, b_all, X, NBOX, HDIM, G3, HDIM, 1);

    // ---- encoder ----
    gemm_f32<<<dim3(G3 / 64, NBOX / 128), 256, 0, stream>>>(
        X, enc_Wih, enc_bih, GIE, NBOX, G3, HDIM, G3, 0);
    gru_scan<<<1, 256, 0, stream>>>(GIE, enc_Whh, enc_bhh, nullptr,
                                    esum, henc, nullptr, NBOX);

    // ---- decoder prep (applied = esum constant across steps) ----
    prep_dec<<<1, 128, 0, stream>>>(esum, W_comb, b_comb, c2);
    gemm_f32<<<dim3(HDIM / 64, NBOX / 128), 256, 0, stream>>>(
        X, W_comb, c2, DIN, NBOX, HDIM, HDIM, HDIM, 1);
    gemm_f32<<<dim3(G3 / 64, NBOX / 128), 256, 0, stream>>>(
        DIN, dec_Wih, dec_bih, GID, NBOX, G3, HDIM, G3, 0);

    // ---- decoder scan ----
    gru_scan<<<1, 256, 0, stream>>>(GID, dec_Whh, dec_bhh, henc,
                                    nullptr, nullptr, D, NBOX);

    // ---- epilogue ----
    out_row<<<NBOX / 4, 256, 0, stream>>>(D, W_out, b_out, out);
    copy_lw<<<NBOX / 256, 256, 0, stream>>>(boxes_label, boxes_weight, out);
}

// Round 11
// 3851.491 us; speedup vs baseline: 1.3516x; 1.0716x over previous
//
#include <hip/hip_runtime.h>
#include <hip/hip_bf16.h>
#include <math.h>

#define NBOX 4096
#define HDIM 128
#define G3   384   // 3*H
#define PF   8     // GI prefetch depth (steps)

typedef _Float16 half2v __attribute__((ext_vector_type(2)));
typedef short bf16x8 __attribute__((ext_vector_type(8)));
typedef float f32x4 __attribute__((ext_vector_type(4)));
#define LDK 40     // LDS row stride in shorts (80B = 5x16B aligned, 2-way banks)

__device__ __forceinline__ float sigm(float x) { return 1.f / (1.f + expf(-x)); }
__device__ __forceinline__ float sigm_fast(float x) {
    return __builtin_amdgcn_rcpf(1.f + __expf(-x));
}
__device__ __forceinline__ float tanh_fast(float x) {
    x = fminf(15.f, fmaxf(-15.f, x));
    const float e2 = __expf(2.f * x);
    return (e2 - 1.f) * __builtin_amdgcn_rcpf(e2 + 1.f);
}
__device__ __forceinline__ float bcast_q1(float x) {
    return __int_as_float(__builtin_amdgcn_mov_dpp(__float_as_int(x), 0x55, 0xF, 0xF, false));
}
__device__ __forceinline__ float bcast_q3(float x) {
    return __int_as_float(__builtin_amdgcn_mov_dpp(__float_as_int(x), 0xFF, 0xF, 0xF, false));
}
__device__ __forceinline__ float qsum(float v) {
    v += __int_as_float(__builtin_amdgcn_mov_dpp(__float_as_int(v), 0xB1, 0xF, 0xF, false));
    v += __int_as_float(__builtin_amdgcn_mov_dpp(__float_as_int(v), 0x4E, 0xF, 0xF, false));
    return v;
}
__device__ __forceinline__ float fdot2(unsigned int h2, unsigned int w2, float acc) {
    return __builtin_amdgcn_fdot2(__builtin_bit_cast(half2v, h2),
                                  __builtin_bit_cast(half2v, w2), acc, false);
}
__device__ __forceinline__ void bar_lds() {
    asm volatile("s_waitcnt lgkmcnt(0)\n\ts_barrier" ::: "memory");
}
__device__ __forceinline__ unsigned short f2bf(float x) {
    return __builtin_bit_cast(unsigned short, __float2bfloat16(x));
}

// C[M,N] = act(A[M,K] @ B[K,N] + bias[N]); row-major. BM=128,BN=64,BK=16.
__global__ __launch_bounds__(256) void gemm_f32(
    const float* __restrict__ A, const float* __restrict__ B,
    const float* __restrict__ bias, float* __restrict__ C,
    int M, int N, int K, int ldc, int act)
{
    __shared__ float As[16][132];
    __shared__ float Bs[16][68];
    const int tid = threadIdx.x;
    const int m0 = blockIdx.y * 128;
    const int n0 = blockIdx.x * 64;
    const int ak = tid & 15, am = tid >> 4;
    const int bn = tid & 63, bk = tid >> 6;
    const int tx = tid & 15, ty = tid >> 4;
    float acc[8][4] = {};
    for (int k0 = 0; k0 < K; k0 += 16) {
#pragma unroll
        for (int r = 0; r < 8; ++r)
            As[ak][am + 16 * r] = A[(size_t)(m0 + am + 16 * r) * K + k0 + ak];
#pragma unroll
        for (int r = 0; r < 4; ++r)
            Bs[bk + 4 * r][bn] = B[(size_t)(k0 + bk + 4 * r) * N + n0 + bn];
        __syncthreads();
#pragma unroll
        for (int k = 0; k < 16; ++k) {
            float4 a0 = *(const float4*)&As[k][ty * 8];
            float4 a1 = *(const float4*)&As[k][ty * 8 + 4];
            float4 b0 = *(const float4*)&Bs[k][tx * 4];
            float a[8] = {a0.x, a0.y, a0.z, a0.w, a1.x, a1.y, a1.z, a1.w};
            float b[4] = {b0.x, b0.y, b0.z, b0.w};
#pragma unroll
            for (int i = 0; i < 8; ++i)
#pragma unroll
                for (int j = 0; j < 4; ++j)
                    acc[i][j] = fmaf(a[i], b[j], acc[i][j]);
        }
        __syncthreads();
    }
#pragma unroll
    for (int i = 0; i < 8; ++i) {
        const int m = m0 + ty * 8 + i;
#pragma unroll
        for (int j = 0; j < 4; ++j) {
            const int n = n0 + tx * 4 + j;
            float v = acc[i][j] + bias[n];
            if (act) v = fmaxf(v, 0.f);
            C[(size_t)m * ldc + n] = v;
        }
    }
}

// Bt[n][k] = bf16(B[k][n]) — one-shot transpose+convert for MFMA B operand.
__global__ __launch_bounds__(256) void conv_bt(
    const float* __restrict__ B, unsigned short* __restrict__ Bt, int K, int N)
{
    const int id = blockIdx.x * 256 + threadIdx.x;
    if (id < K * N) {
        const int n = id / K, k = id % K;      // write-coalesced along k
        Bt[(size_t)n * K + k] = f2bf(B[(size_t)k * N + n]);
    }
}

// C[M,N] = act(A@B + bias), A f32 [M][K] (converted to bf16 in staging),
// Bt bf16 [N][K] (pre-transposed). 128x128 tile, 4 waves, 16x16x32 MFMA.
// Fragment layout (guide §3, m89-verified): A/B lane: idx=l&15, k-octet=l>>4;
// C/D: col=l&15, row=(l>>4)*4+reg.
__global__ __launch_bounds__(256) void gemm_bf16t(
    const float* __restrict__ A, const unsigned short* __restrict__ Bt,
    const float* __restrict__ bias, float* __restrict__ C,
    int M, int N, int K, int ldc, int act)
{
    __shared__ unsigned short As[128][LDK];
    __shared__ unsigned short Bs[128][LDK];
    const int tid = threadIdx.x;
    const int m0 = blockIdx.y * 128, n0 = blockIdx.x * 128;
    const int wv = tid >> 6, lane = tid & 63;
    const int wr = (wv >> 1) * 64, wc = (wv & 1) * 64;
    const int lr = lane & 15, lk = lane >> 4;
    const int sm = tid >> 1, skh = (tid & 1) * 16;   // staging: row, k-half
    f32x4 acc[4][4] = {};
    for (int k0 = 0; k0 < K; k0 += 32) {
        // stage A: 16 f32 -> 16 bf16 -> 2x b128
        const float* ga = &A[(size_t)(m0 + sm) * K + k0 + skh];
        float4 f0 = *(const float4*)(ga + 0);
        float4 f1 = *(const float4*)(ga + 4);
        float4 f2 = *(const float4*)(ga + 8);
        float4 f3 = *(const float4*)(ga + 12);
        const float fa[16] = {f0.x,f0.y,f0.z,f0.w, f1.x,f1.y,f1.z,f1.w,
                              f2.x,f2.y,f2.z,f2.w, f3.x,f3.y,f3.z,f3.w};
        unsigned int pk[8];
#pragma unroll
        for (int e = 0; e < 8; ++e)
            pk[e] = (unsigned int)f2bf(fa[2*e]) | ((unsigned int)f2bf(fa[2*e+1]) << 16);
        *(uint4*)&As[sm][skh]     = make_uint4(pk[0], pk[1], pk[2], pk[3]);
        *(uint4*)&As[sm][skh + 8] = make_uint4(pk[4], pk[5], pk[6], pk[7]);
        // stage Bt: already bf16, contiguous
        const uint4* gb = (const uint4*)&Bt[(size_t)(n0 + sm) * K + k0 + skh];
        *(uint4*)&Bs[sm][skh]     = gb[0];
        *(uint4*)&Bs[sm][skh + 8] = gb[1];
        __syncthreads();
        bf16x8 af[4], bfr[4];
#pragma unroll
        for (int f = 0; f < 4; ++f) {
            af[f]  = *(const bf16x8*)&As[wr + f * 16 + lr][lk * 8];
            bfr[f] = *(const bf16x8*)&Bs[wc + f * 16 + lr][lk * 8];
        }
#pragma unroll
        for (int i = 0; i < 4; ++i)
#pragma unroll
            for (int j = 0; j < 4; ++j)
                acc[i][j] = __builtin_amdgcn_mfma_f32_16x16x32_bf16(
                    af[i], bfr[j], acc[i][j], 0, 0, 0);
        __syncthreads();
    }
#pragma unroll
    for (int i = 0; i < 4; ++i)
#pragma unroll
        for (int j = 0; j < 4; ++j)
#pragma unroll
            for (int r = 0; r < 4; ++r) {
                const int row = m0 + wr + i * 16 + lk * 4 + r;
                const int col = n0 + wc + j * 16 + lr;
                float v = acc[i][j][r] + bias[col];
                if (act) v = fmaxf(v, 0.f);
                C[(size_t)row * ldc + col] = v;
            }
}

// Sequential GRU scan (round-10 structure, FROZEN): 256 threads, 4 waves
// 1/SIMD, quad-K-split, f16 dot2 matvec, register-carried hp, lgkm-only
// barrier, PF-deep GI prefetch. ~994 cyc/step, near VALU-issue+chain bound.
__global__ __launch_bounds__(256)
__attribute__((amdgpu_waves_per_eu(1, 1)))
void gru_scan(
    const float* __restrict__ GI, const float* __restrict__ Whh,
    const float* __restrict__ bhh, const float* __restrict__ h0,
    double* __restrict__ esum_out, float* __restrict__ hfinal_out,
    float* __restrict__ D_out, int T)
{
    __shared__ unsigned short h16[2][HDIM];
    const int tid = threadIdx.x;
    const int j = tid >> 2;
    const int g = tid & 3;
    const int qa = 2 * j, qb = 2 * j + 1;
    const int myq = (g & 2) ? qb : qa;
    const int colS = ((g & 1) ? HDIM : 0) + myq;
    const int colT = 2 * HDIM + myq;
    unsigned int w[96];
#pragma unroll
    for (int c6 = 0; c6 < 6; ++c6) {
        const int cc = (c6 % 3) * HDIM + ((c6 < 3) ? qa : qb);
#pragma unroll
        for (int p2 = 0; p2 < 16; ++p2) {
            const int k = 32 * g + 2 * p2;
            const _Float16 lo = (_Float16)Whh[(size_t)k * G3 + cc];
            const _Float16 hi = (_Float16)Whh[(size_t)(k + 1) * G3 + cc];
            w[c6 * 16 + p2] = (unsigned int)__builtin_bit_cast(unsigned short, lo)
                            | ((unsigned int)__builtin_bit_cast(unsigned short, hi) << 16);
        }
    }
#pragma unroll
    for (int p = 0; p < 96; ++p) asm volatile("" : "+v"(w[p]));
    const float bS = bhh[colS];
    const float bT = bhh[colT];
    if (tid < HDIM)
        h16[0][tid] = __builtin_bit_cast(unsigned short,
                                         (_Float16)(h0 ? h0[tid] : 0.f));
    float hp = (float)(_Float16)(h0 ? h0[myq] : 0.f);
    double esum = 0.0;
    float gS[PF], gT[PF], gSn[PF], gTn[PF];
#pragma unroll
    for (int p = 0; p < PF; ++p) {
        gS[p] = GI[(size_t)p * G3 + colS];
        gT[p] = GI[(size_t)p * G3 + colT];
    }
    __syncthreads();
    for (int t0 = 0; t0 < T; t0 += PF) {
#pragma unroll
        for (int p = 0; p < PF; ++p) {
            gSn[p] = GI[(size_t)(t0 + PF + p) * G3 + colS];
            gTn[p] = GI[(size_t)(t0 + PF + p) * G3 + colT];
        }
#pragma unroll
        for (int p = 0; p < PF; ++p) {
            const int t = t0 + p;
            const uint4* hb = (const uint4*)h16[t & 1];
            uint4 uu[4];
#pragma unroll
            for (int pp = 0; pp < 4; ++pp) uu[pp] = hb[4 * g + pp];
            float s0 = 0.f, s1 = 0.f, s2 = 0.f, s3 = 0.f, s4 = 0.f, s5 = 0.f;
#pragma unroll
            for (int pp = 0; pp < 4; ++pp) {
                const unsigned int x[4] = {uu[pp].x, uu[pp].y, uu[pp].z, uu[pp].w};
#pragma unroll
                for (int i2 = 0; i2 < 4; ++i2) {
                    const int pi = 4 * pp + i2;
                    s0 = fdot2(x[i2], w[pi], s0);
                    s1 = fdot2(x[i2], w[16 + pi], s1);
                    s2 = fdot2(x[i2], w[32 + pi], s2);
                    s3 = fdot2(x[i2], w[48 + pi], s3);
                    s4 = fdot2(x[i2], w[64 + pi], s4);
                    s5 = fdot2(x[i2], w[80 + pi], s5);
                }
            }
            s0 = qsum(s0); s1 = qsum(s1); s2 = qsum(s2);
            s3 = qsum(s3); s4 = qsum(s4); s5 = qsum(s5);
            const float ghS = ((g & 2) ? ((g & 1) ? s4 : s3)
                                       : ((g & 1) ? s1 : s0)) + bS;
            const float ghT = ((g & 2) ? s5 : s2) + bT;
            const float s = sigm_fast(gS[p] + ghS);
            const float n = tanh_fast(gT[p] + s * ghT);
            const float z1 = bcast_q1(s);
            const float z3 = bcast_q3(s);
            const float z = (g & 2) ? z3 : z1;
            const float hn = z * (hp - n) + n;
            if (!(g & 1)) {
                h16[(t + 1) & 1][myq] =
                    __builtin_bit_cast(unsigned short, (_Float16)hn);
                esum += (double)hn;
                if (D_out) D_out[(size_t)t * HDIM + myq] = hn;
            }
            hp = (float)(_Float16)hn;
            bar_lds();
        }
#pragma unroll
        for (int p = 0; p < PF; ++p) { gS[p] = gSn[p]; gT[p] = gTn[p]; }
    }
    if (!(g & 1)) {
        if (esum_out) esum_out[myq] = esum;
        if (hfinal_out) hfinal_out[myq] = hp;
    }
}

// c2[j] = b_comb[j] + sum_k esum[k] * W_comb[128+k][j]
__global__ void prep_dec(const double* __restrict__ esum, const float* __restrict__ W_comb,
                         const float* __restrict__ b_comb, float* __restrict__ c2)
{
    __shared__ double es[HDIM];
    const int j = threadIdx.x;
    es[j] = esum[j];
    __syncthreads();
    double acc = (double)b_comb[j];
    for (int k = 0; k < HDIM; ++k)
        acc += es[k] * (double)W_comb[(HDIM + k) * HDIM + j];
    c2[j] = (float)acc;
}

__global__ __launch_bounds__(256) void out_row(
    const float* __restrict__ D, const float* __restrict__ Wout,
    const float* __restrict__ b_out, float* __restrict__ out)
{
    const int row = (blockIdx.x * 256 + threadIdx.x) >> 6;
    const int lane = threadIdx.x & 63;
    float v = D[(size_t)row * HDIM + lane] * Wout[lane]
            + D[(size_t)row * HDIM + 64 + lane] * Wout[64 + lane];
#pragma unroll
    for (int s = 32; s > 0; s >>= 1) v += __shfl_down(v, s);
    if (lane == 0) out[row] = sigm(v + b_out[0]);
}

__global__ void copy_lw(const float* __restrict__ lab, const float* __restrict__ wt,
                        float* __restrict__ out)
{
    const int i = blockIdx.x * 256 + threadIdx.x;
    if (i < NBOX) { out[NBOX + i] = lab[i]; out[2 * NBOX + i] = wt[i]; }
}

extern "C" void kernel_launch(void* const* d_in, const int* in_sizes, int n_in,
                              void* d_out, int out_size, void* d_ws, size_t ws_size,
                              hipStream_t stream)
{
    const float* boxes_feature = (const float*)d_in[0];
    const float* boxes_score   = (const float*)d_in[1];
    const float* boxes_box     = (const float*)d_in[2];
    const float* boxes_label   = (const float*)d_in[3];
    const float* boxes_weight  = (const float*)d_in[4];
    const float* W_appear = (const float*)d_in[6];
    const float* b_appear = (const float*)d_in[7];
    const float* W_s1     = (const float*)d_in[8];
    const float* b_s1     = (const float*)d_in[9];
    const float* W_s2     = (const float*)d_in[10];
    const float* b_s2     = (const float*)d_in[11];
    const float* W_box    = (const float*)d_in[12];
    const float* b_box    = (const float*)d_in[13];
    const float* W_all    = (const float*)d_in[14];
    const float* b_all    = (const float*)d_in[15];
    const float* enc_Wih  = (const float*)d_in[16];
    const float* enc_Whh  = (const float*)d_in[17];
    const float* enc_bih  = (const float*)d_in[18];
    const float* enc_bhh  = (const float*)d_in[19];
    const float* dec_Wih  = (const float*)d_in[20];
    const float* dec_Whh  = (const float*)d_in[21];
    const float* dec_bih  = (const float*)d_in[22];
    const float* dec_bhh  = (const float*)d_in[23];
    // d_in[24] W_attn, d_in[25] b_attn: no effect (softmax over singleton)
    const float* W_comb   = (const float*)d_in[26];
    const float* b_comb   = (const float*)d_in[27];
    const float* W_out    = (const float*)d_in[28];
    const float* b_out    = (const float*)d_in[29];

    float* out = (float*)d_out;
    float* ws = (float*)d_ws;
    size_t o = 0;
    float* T1   = ws + o; o += (size_t)NBOX * 512;      // score@W_s1+b (LINEAR)
    float* XCAT = ws + o; o += (size_t)NBOX * G3;
    float* X    = ws + o; o += (size_t)NBOX * HDIM;
    float* GIE  = ws + o; o += (size_t)(NBOX + PF) * G3;  // padded for prefetch
    float* GID  = ws + o; o += (size_t)(NBOX + PF) * G3;
    float* DIN  = ws + o; o += (size_t)NBOX * HDIM;
    float* D    = ws + o; o += (size_t)NBOX * HDIM;
    o = (o + 1) & ~(size_t)1;
    double* esum = (double*)(ws + o); o += 256;
    float* henc = ws + o; o += 128;
    float* c2   = ws + o; o += 128;
    // W_s1^T bf16 (512*2560 shorts = 655360 floats) ALIASED into GIE: it is
    // consumed by gemm_bf16t strictly BEFORE the X@enc_Wih GEMM writes GIE.
    unsigned short* Wt_bf = (unsigned short*)GIE;

    // ---- phase 1 ----
    conv_bt<<<(2560 * 512 + 255) / 256, 256, 0, stream>>>(W_s1, Wt_bf, 2560, 512);
    gemm_bf16t<<<dim3(512 / 128, NBOX / 128), 256, 0, stream>>>(
        boxes_score, Wt_bf, b_s1, T1, NBOX, 512, 2560, 512, 0);  // LINEAR
    gemm_f32<<<dim3(HDIM / 64, NBOX / 128), 256, 0, stream>>>(
        boxes_feature, W_appear, b_appear, XCAT + 0, NBOX, HDIM, 1024, G3, 1);
    gemm_f32<<<dim3(HDIM / 64, NBOX / 128), 256, 0, stream>>>(
        T1, W_s2, b_s2, XCAT + HDIM, NBOX, HDIM, 512, G3, 1);
    gemm_f32<<<dim3(HDIM / 64, NBOX / 128), 256, 0, stream>>>(
        boxes_box, W_box, b_box, XCAT + 2 * HDIM, NBOX, HDIM, 320, G3, 1);
    gemm_f32<<<dim3(HDIM / 64, NBOX / 128), 256, 0, stream>>>(
        XCAT, W_all, b_all, X, NBOX, HDIM, G3, HDIM, 1);

    // ---- encoder ----
    gemm_f32<<<dim3(G3 / 64, NBOX / 128), 256, 0, stream>>>(
        X, enc_Wih, enc_bih, GIE, NBOX, G3, HDIM, G3, 0);
    gru_scan<<<1, 256, 0, stream>>>(GIE, enc_Whh, enc_bhh, nullptr,
                                    esum, henc, nullptr, NBOX);

    // ---- decoder prep (applied = esum constant across steps) ----
    prep_dec<<<1, 128, 0, stream>>>(esum, W_comb, b_comb, c2);
    gemm_f32<<<dim3(HDIM / 64, NBOX / 128), 256, 0, stream>>>(
        X, W_comb, c2, DIN, NBOX, HDIM, HDIM, HDIM, 1);
    gemm_f32<<<dim3(G3 / 64, NBOX / 128), 256, 0, stream>>>(
        DIN, dec_Wih, dec_bih, GID, NBOX, G3, HDIM, G3, 0);

    // ---- decoder scan ----
    gru_scan<<<1, 256, 0, stream>>>(GID, dec_Whh, dec_bhh, henc,
                                    nullptr, nullptr, D, NBOX);

    // ---- epilogue ----
    out_row<<<NBOX / 4, 256, 0, stream>>>(D, W_out, b_out, out);
    copy_lw<<<NBOX / 256, 256, 0, stream>>>(boxes_label, boxes_weight, out);
}

// Round 12
// 3603.146 us; speedup vs baseline: 1.4447x; 1.0689x over previous
//
#include <hip/hip_runtime.h>
#include <hip/hip_bf16.h>
#include <math.h>

#define NBOX 4096
#define HDIM 128
#define G3   384   // 3*H
#define PF   8     // GI prefetch depth (steps)

typedef _Float16 half2v __attribute__((ext_vector_type(2)));
typedef short bf16x8 __attribute__((ext_vector_type(8)));
typedef float f32x4 __attribute__((ext_vector_type(4)));
#define LDK 40     // LDS row stride in shorts (80B, 16B-aligned, 2-way banks)

__device__ __forceinline__ float sigm(float x) { return 1.f / (1.f + expf(-x)); }
__device__ __forceinline__ float sigm_fast(float x) {
    return __builtin_amdgcn_rcpf(1.f + __expf(-x));
}
__device__ __forceinline__ float tanh_fast(float x) {
    x = fminf(15.f, fmaxf(-15.f, x));
    const float e2 = __expf(2.f * x);
    return (e2 - 1.f) * __builtin_amdgcn_rcpf(e2 + 1.f);
}
__device__ __forceinline__ float bcast_q1(float x) {
    return __int_as_float(__builtin_amdgcn_mov_dpp(__float_as_int(x), 0x55, 0xF, 0xF, false));
}
__device__ __forceinline__ float bcast_q3(float x) {
    return __int_as_float(__builtin_amdgcn_mov_dpp(__float_as_int(x), 0xFF, 0xF, 0xF, false));
}
__device__ __forceinline__ float qsum(float v) {
    v += __int_as_float(__builtin_amdgcn_mov_dpp(__float_as_int(v), 0xB1, 0xF, 0xF, false));
    v += __int_as_float(__builtin_amdgcn_mov_dpp(__float_as_int(v), 0x4E, 0xF, 0xF, false));
    return v;
}
__device__ __forceinline__ float fdot2(unsigned int h2, unsigned int w2, float acc) {
    return __builtin_amdgcn_fdot2(__builtin_bit_cast(half2v, h2),
                                  __builtin_bit_cast(half2v, w2), acc, false);
}
__device__ __forceinline__ void bar_lds() {
    asm volatile("s_waitcnt lgkmcnt(0)\n\ts_barrier" ::: "memory");
}
__device__ __forceinline__ unsigned short f2bf(float x) {
    return __builtin_bit_cast(unsigned short, __float2bfloat16(x));
}

// Bt[n][k] = bf16(B[k][n]) — transpose+convert for the MFMA B operand.
__global__ __launch_bounds__(256) void conv_bt(
    const float* __restrict__ B, unsigned short* __restrict__ Bt, int K, int N)
{
    const int id = blockIdx.x * 256 + threadIdx.x;
    if (id < K * N) {
        const int n = id / K, k = id % K;      // write-coalesced along k
        Bt[(size_t)n * K + k] = f2bf(B[(size_t)k * N + n]);
    }
}

// C[M,N] = act(A@B + bias), A f32 [M][K] (bf16-converted in staging),
// Bt bf16 [N][K] (pre-transposed). 128x128 tile, 4 waves, 16x16x32 MFMA.
// Fragment layout (guide §3, m89-verified): A/B lane: idx=l&15, k-octet=l>>4;
// C/D: col=l&15, row=(l>>4)*4+reg. Verified r11 (absmax unchanged).
__global__ __launch_bounds__(256) void gemm_bf16t(
    const float* __restrict__ A, const unsigned short* __restrict__ Bt,
    const float* __restrict__ bias, float* __restrict__ C,
    int M, int N, int K, int ldc, int act)
{
    __shared__ unsigned short As[128][LDK];
    __shared__ unsigned short Bs[128][LDK];
    const int tid = threadIdx.x;
    const int m0 = blockIdx.y * 128, n0 = blockIdx.x * 128;
    const int wv = tid >> 6, lane = tid & 63;
    const int wr = (wv >> 1) * 64, wc = (wv & 1) * 64;
    const int lr = lane & 15, lk = lane >> 4;
    const int sm = tid >> 1, skh = (tid & 1) * 16;   // staging: row, k-half
    f32x4 acc[4][4] = {};
    for (int k0 = 0; k0 < K; k0 += 32) {
        const float* ga = &A[(size_t)(m0 + sm) * K + k0 + skh];
        float4 f0 = *(const float4*)(ga + 0);
        float4 f1 = *(const float4*)(ga + 4);
        float4 f2 = *(const float4*)(ga + 8);
        float4 f3 = *(const float4*)(ga + 12);
        const float fa[16] = {f0.x,f0.y,f0.z,f0.w, f1.x,f1.y,f1.z,f1.w,
                              f2.x,f2.y,f2.z,f2.w, f3.x,f3.y,f3.z,f3.w};
        unsigned int pk[8];
#pragma unroll
        for (int e = 0; e < 8; ++e)
            pk[e] = (unsigned int)f2bf(fa[2*e]) | ((unsigned int)f2bf(fa[2*e+1]) << 16);
        *(uint4*)&As[sm][skh]     = make_uint4(pk[0], pk[1], pk[2], pk[3]);
        *(uint4*)&As[sm][skh + 8] = make_uint4(pk[4], pk[5], pk[6], pk[7]);
        const uint4* gb = (const uint4*)&Bt[(size_t)(n0 + sm) * K + k0 + skh];
        *(uint4*)&Bs[sm][skh]     = gb[0];
        *(uint4*)&Bs[sm][skh + 8] = gb[1];
        __syncthreads();
        bf16x8 af[4], bfr[4];
#pragma unroll
        for (int f = 0; f < 4; ++f) {
            af[f]  = *(const bf16x8*)&As[wr + f * 16 + lr][lk * 8];
            bfr[f] = *(const bf16x8*)&Bs[wc + f * 16 + lr][lk * 8];
        }
#pragma unroll
        for (int i = 0; i < 4; ++i)
#pragma unroll
            for (int j = 0; j < 4; ++j)
                acc[i][j] = __builtin_amdgcn_mfma_f32_16x16x32_bf16(
                    af[i], bfr[j], acc[i][j], 0, 0, 0);
        __syncthreads();
    }
#pragma unroll
    for (int i = 0; i < 4; ++i)
#pragma unroll
        for (int j = 0; j < 4; ++j)
#pragma unroll
            for (int r = 0; r < 4; ++r) {
                const int row = m0 + wr + i * 16 + lk * 4 + r;
                const int col = n0 + wc + j * 16 + lr;
                float v = acc[i][j][r] + bias[col];
                if (act) v = fmaxf(v, 0.f);
                C[(size_t)row * ldc + col] = v;
            }
}

// Sequential GRU scan (round-10 structure, FROZEN): 256 threads, 4 waves
// 1/SIMD, quad-K-split, f16 dot2 matvec, register-carried hp, lgkm-only
// barrier, PF-deep GI prefetch. ~994 cyc/step (issue+chain bound).
__global__ __launch_bounds__(256)
__attribute__((amdgpu_waves_per_eu(1, 1)))
void gru_scan(
    const float* __restrict__ GI, const float* __restrict__ Whh,
    const float* __restrict__ bhh, const float* __restrict__ h0,
    double* __restrict__ esum_out, float* __restrict__ hfinal_out,
    float* __restrict__ D_out, int T)
{
    __shared__ unsigned short h16[2][HDIM];
    const int tid = threadIdx.x;
    const int j = tid >> 2;
    const int g = tid & 3;
    const int qa = 2 * j, qb = 2 * j + 1;
    const int myq = (g & 2) ? qb : qa;
    const int colS = ((g & 1) ? HDIM : 0) + myq;
    const int colT = 2 * HDIM + myq;
    unsigned int w[96];
#pragma unroll
    for (int c6 = 0; c6 < 6; ++c6) {
        const int cc = (c6 % 3) * HDIM + ((c6 < 3) ? qa : qb);
#pragma unroll
        for (int p2 = 0; p2 < 16; ++p2) {
            const int k = 32 * g + 2 * p2;
            const _Float16 lo = (_Float16)Whh[(size_t)k * G3 + cc];
            const _Float16 hi = (_Float16)Whh[(size_t)(k + 1) * G3 + cc];
            w[c6 * 16 + p2] = (unsigned int)__builtin_bit_cast(unsigned short, lo)
                            | ((unsigned int)__builtin_bit_cast(unsigned short, hi) << 16);
        }
    }
#pragma unroll
    for (int p = 0; p < 96; ++p) asm volatile("" : "+v"(w[p]));
    const float bS = bhh[colS];
    const float bT = bhh[colT];
    if (tid < HDIM)
        h16[0][tid] = __builtin_bit_cast(unsigned short,
                                         (_Float16)(h0 ? h0[tid] : 0.f));
    float hp = (float)(_Float16)(h0 ? h0[myq] : 0.f);
    double esum = 0.0;
    float gS[PF], gT[PF], gSn[PF], gTn[PF];
#pragma unroll
    for (int p = 0; p < PF; ++p) {
        gS[p] = GI[(size_t)p * G3 + colS];
        gT[p] = GI[(size_t)p * G3 + colT];
    }
    __syncthreads();
    for (int t0 = 0; t0 < T; t0 += PF) {
#pragma unroll
        for (int p = 0; p < PF; ++p) {
            gSn[p] = GI[(size_t)(t0 + PF + p) * G3 + colS];
            gTn[p] = GI[(size_t)(t0 + PF + p) * G3 + colT];
        }
#pragma unroll
        for (int p = 0; p < PF; ++p) {
            const int t = t0 + p;
            const uint4* hb = (const uint4*)h16[t & 1];
            uint4 uu[4];
#pragma unroll
            for (int pp = 0; pp < 4; ++pp) uu[pp] = hb[4 * g + pp];
            float s0 = 0.f, s1 = 0.f, s2 = 0.f, s3 = 0.f, s4 = 0.f, s5 = 0.f;
#pragma unroll
            for (int pp = 0; pp < 4; ++pp) {
                const unsigned int x[4] = {uu[pp].x, uu[pp].y, uu[pp].z, uu[pp].w};
#pragma unroll
                for (int i2 = 0; i2 < 4; ++i2) {
                    const int pi = 4 * pp + i2;
                    s0 = fdot2(x[i2], w[pi], s0);
                    s1 = fdot2(x[i2], w[16 + pi], s1);
                    s2 = fdot2(x[i2], w[32 + pi], s2);
                    s3 = fdot2(x[i2], w[48 + pi], s3);
                    s4 = fdot2(x[i2], w[64 + pi], s4);
                    s5 = fdot2(x[i2], w[80 + pi], s5);
                }
            }
            s0 = qsum(s0); s1 = qsum(s1); s2 = qsum(s2);
            s3 = qsum(s3); s4 = qsum(s4); s5 = qsum(s5);
            const float ghS = ((g & 2) ? ((g & 1) ? s4 : s3)
                                       : ((g & 1) ? s1 : s0)) + bS;
            const float ghT = ((g & 2) ? s5 : s2) + bT;
            const float s = sigm_fast(gS[p] + ghS);
            const float n = tanh_fast(gT[p] + s * ghT);
            const float z1 = bcast_q1(s);
            const float z3 = bcast_q3(s);
            const float z = (g & 2) ? z3 : z1;
            const float hn = z * (hp - n) + n;
            if (!(g & 1)) {
                h16[(t + 1) & 1][myq] =
                    __builtin_bit_cast(unsigned short, (_Float16)hn);
                esum += (double)hn;
                if (D_out) D_out[(size_t)t * HDIM + myq] = hn;
            }
            hp = (float)(_Float16)hn;
            bar_lds();
        }
#pragma unroll
        for (int p = 0; p < PF; ++p) { gS[p] = gSn[p]; gT[p] = gTn[p]; }
    }
    if (!(g & 1)) {
        if (esum_out) esum_out[myq] = esum;
        if (hfinal_out) hfinal_out[myq] = hp;
    }
}

// c2[j] = b_comb[j] + sum_k esum[k] * W_comb[128+k][j]
__global__ void prep_dec(const double* __restrict__ esum, const float* __restrict__ W_comb,
                         const float* __restrict__ b_comb, float* __restrict__ c2)
{
    __shared__ double es[HDIM];
    const int j = threadIdx.x;
    es[j] = esum[j];
    __syncthreads();
    double acc = (double)b_comb[j];
    for (int k = 0; k < HDIM; ++k)
        acc += es[k] * (double)W_comb[(HDIM + k) * HDIM + j];
    c2[j] = (float)acc;
}

// blocks [0,1024): out[row] = sigmoid(D[row].Wout + b); blocks >=1024: copy.
__global__ __launch_bounds__(256) void epilogue(
    const float* __restrict__ D, const float* __restrict__ Wout,
    const float* __restrict__ b_out, const float* __restrict__ lab,
    const float* __restrict__ wt, float* __restrict__ out)
{
    const int bid = blockIdx.x;
    if (bid < 1024) {
        const int row = (bid * 256 + threadIdx.x) >> 6;
        const int lane = threadIdx.x & 63;
        float v = D[(size_t)row * HDIM + lane] * Wout[lane]
                + D[(size_t)row * HDIM + 64 + lane] * Wout[64 + lane];
#pragma unroll
        for (int s = 32; s > 0; s >>= 1) v += __shfl_down(v, s);
        if (lane == 0) out[row] = sigm(v + b_out[0]);
    } else {
        const int i = (bid - 1024) * 256 + threadIdx.x;   // 0..8191
        out[NBOX + i] = (i < NBOX) ? lab[i] : wt[i - NBOX];
    }
}

extern "C" void kernel_launch(void* const* d_in, const int* in_sizes, int n_in,
                              void* d_out, int out_size, void* d_ws, size_t ws_size,
                              hipStream_t stream)
{
    const float* boxes_feature = (const float*)d_in[0];
    const float* boxes_score   = (const float*)d_in[1];
    const float* boxes_box     = (const float*)d_in[2];
    const float* boxes_label   = (const float*)d_in[3];
    const float* boxes_weight  = (const float*)d_in[4];
    const float* W_appear = (const float*)d_in[6];
    const float* b_appear = (const float*)d_in[7];
    const float* W_s1     = (const float*)d_in[8];
    const float* b_s1     = (const float*)d_in[9];
    const float* W_s2     = (const float*)d_in[10];
    const float* b_s2     = (const float*)d_in[11];
    const float* W_box    = (const float*)d_in[12];
    const float* b_box    = (const float*)d_in[13];
    const float* W_all    = (const float*)d_in[14];
    const float* b_all    = (const float*)d_in[15];
    const float* enc_Wih  = (const float*)d_in[16];
    const float* enc_Whh  = (const float*)d_in[17];
    const float* enc_bih  = (const float*)d_in[18];
    const float* enc_bhh  = (const float*)d_in[19];
    const float* dec_Wih  = (const float*)d_in[20];
    const float* dec_Whh  = (const float*)d_in[21];
    const float* dec_bih  = (const float*)d_in[22];
    const float* dec_bhh  = (const float*)d_in[23];
    // d_in[24] W_attn, d_in[25] b_attn: no effect (softmax over singleton)
    const float* W_comb   = (const float*)d_in[26];
    const float* b_comb   = (const float*)d_in[27];
    const float* W_out    = (const float*)d_in[28];
    const float* b_out    = (const float*)d_in[29];

    float* out = (float*)d_out;
    float* ws = (float*)d_ws;
    size_t o = 0;
    float* T1   = ws + o; o += (size_t)NBOX * 512;      // score@W_s1+b (LINEAR)
    float* XCAT = ws + o; o += (size_t)NBOX * G3;
    float* X    = ws + o; o += (size_t)NBOX * HDIM;
    float* GIE  = ws + o; o += (size_t)(NBOX + PF) * G3;  // padded for prefetch
    float* GID  = ws + o; o += (size_t)(NBOX + PF) * G3;
    float* DIN  = ws + o; o += (size_t)NBOX * HDIM;
    float* D    = ws + o; o += (size_t)NBOX * HDIM;
    o = (o + 1) & ~(size_t)1;
    double* esum = (double*)(ws + o); o += 256;
    float* henc = ws + o; o += 128;
    float* c2   = ws + o; o += 128;

    // bf16-transposed weights ALIASED into regions written only later:
    //  - GIE region (3.15M shorts): W_s1^T, W_appear^T, W_s2^T, W_box^T,
    //    W_all^T — all consumed by phase-1 GEMMs before GIE is written.
    //  - GID region: enc_Wih^T, W_comb^T — consumed before GID is written.
    //  - D region: dec_Wih^T — consumed (GID GEMM) before the decoder scan
    //    writes D. All offsets 16B-aligned.
    unsigned short* ws1t  = (unsigned short*)GIE;             // 2560*512
    unsigned short* wappt = ws1t + 1310720;                   // 1024*128
    unsigned short* ws2t  = wappt + 131072;                   // 512*128
    unsigned short* wboxt = ws2t + 65536;                     // 320*128
    unsigned short* wallt = wboxt + 40960;                    // 384*128
    unsigned short* encwt = (unsigned short*)GID;             // 128*384
    unsigned short* wcombt = encwt + 49152;                   // 128*128
    unsigned short* decwt = (unsigned short*)D;               // 128*384

    // ---- weight transposes (independent, run back-to-back) ----
    conv_bt<<<(2560*512 + 255)/256, 256, 0, stream>>>(W_s1,    ws1t,  2560, 512);
    conv_bt<<<(1024*128 + 255)/256, 256, 0, stream>>>(W_appear, wappt, 1024, 128);
    conv_bt<<<( 512*128 + 255)/256, 256, 0, stream>>>(W_s2,    ws2t,   512, 128);
    conv_bt<<<( 320*128 + 255)/256, 256, 0, stream>>>(W_box,   wboxt,  320, 128);
    conv_bt<<<( 384*128 + 255)/256, 256, 0, stream>>>(W_all,   wallt,  384, 128);
    conv_bt<<<( 128*384 + 255)/256, 256, 0, stream>>>(enc_Wih, encwt,  128, 384);
    conv_bt<<<( 128*128 + 255)/256, 256, 0, stream>>>(W_comb,  wcombt, 128, 128);
    conv_bt<<<( 128*384 + 255)/256, 256, 0, stream>>>(dec_Wih, decwt,  128, 384);

    // ---- phase 1: feature GEMMs (all MFMA) ----
    gemm_bf16t<<<dim3(4, 32), 256, 0, stream>>>(
        boxes_score, ws1t, b_s1, T1, NBOX, 512, 2560, 512, 0);   // LINEAR
    gemm_bf16t<<<dim3(1, 32), 256, 0, stream>>>(
        boxes_feature, wappt, b_appear, XCAT + 0, NBOX, 128, 1024, G3, 1);
    gemm_bf16t<<<dim3(1, 32), 256, 0, stream>>>(
        T1, ws2t, b_s2, XCAT + HDIM, NBOX, 128, 512, G3, 1);
    gemm_bf16t<<<dim3(1, 32), 256, 0, stream>>>(
        boxes_box, wboxt, b_box, XCAT + 2 * HDIM, NBOX, 128, 320, G3, 1);
    gemm_bf16t<<<dim3(1, 32), 256, 0, stream>>>(
        XCAT, wallt, b_all, X, NBOX, 128, 384, HDIM, 1);

    // ---- encoder ----
    gemm_bf16t<<<dim3(3, 32), 256, 0, stream>>>(
        X, encwt, enc_bih, GIE, NBOX, 384, 128, G3, 0);
    gru_scan<<<1, 256, 0, stream>>>(GIE, enc_Whh, enc_bhh, nullptr,
                                    esum, henc, nullptr, NBOX);

    // ---- decoder prep (applied = esum constant across steps) ----
    prep_dec<<<1, 128, 0, stream>>>(esum, W_comb, b_comb, c2);
    gemm_bf16t<<<dim3(1, 32), 256, 0, stream>>>(
        X, wcombt, c2, DIN, NBOX, 128, 128, HDIM, 1);
    gemm_bf16t<<<dim3(3, 32), 256, 0, stream>>>(
        DIN, decwt, dec_bih, GID, NBOX, 384, 128, G3, 0);

    // ---- decoder scan ----
    gru_scan<<<1, 256, 0, stream>>>(GID, dec_Whh, dec_bhh, henc,
                                    nullptr, nullptr, D, NBOX);

    // ---- epilogue (row-dot + label/weight copy fused) ----
    epilogue<<<1024 + 32, 256, 0, stream>>>(D, W_out, b_out,
                                            boxes_label, boxes_weight, out);
}

// Round 13
// 3358.883 us; speedup vs baseline: 1.5498x; 1.0727x over previous
//
#include <hip/hip_runtime.h>
#include <hip/hip_bf16.h>
#include <math.h>

#define NBOX 4096
#define HDIM 128
#define G3   384   // 3*H
#define PF   8     // GI prefetch depth (steps)

typedef _Float16 half2v __attribute__((ext_vector_type(2)));
typedef short bf16x8 __attribute__((ext_vector_type(8)));
typedef float f32x4 __attribute__((ext_vector_type(4)));
#define LDK 40     // LDS row stride in shorts (80B, 16B-aligned, 2-way banks)

__device__ __forceinline__ float sigm(float x) { return 1.f / (1.f + expf(-x)); }
__device__ __forceinline__ float sigm_fast(float x) {
    return __builtin_amdgcn_rcpf(1.f + __expf(-x));
}
__device__ __forceinline__ float tanh_fast(float x) {
    // clamp REQUIRED: decoder gT reaches O(+-70); e^{2x} would overflow -> NaN
    x = fminf(15.f, fmaxf(-15.f, x));
    const float e2 = __expf(2.f * x);
    return (e2 - 1.f) * __builtin_amdgcn_rcpf(e2 + 1.f);
}
__device__ __forceinline__ float bcast_q1(float x) {
    return __int_as_float(__builtin_amdgcn_mov_dpp(__float_as_int(x), 0x55, 0xF, 0xF, false));
}
__device__ __forceinline__ float bcast_q3(float x) {
    return __int_as_float(__builtin_amdgcn_mov_dpp(__float_as_int(x), 0xFF, 0xF, 0xF, false));
}
// quad all-reduce sum, FUSED dpp-add form (round 13): one v_add_f32_dpp per
// butterfly stage instead of mov_dpp+add — halves the reduce instruction count.
__device__ __forceinline__ float qsum(float v) {
    asm("v_add_f32_dpp %0, %0, %0 quad_perm:[1,0,3,2] row_mask:0xf bank_mask:0xf"
        : "+v"(v));
    asm("v_add_f32_dpp %0, %0, %0 quad_perm:[2,3,0,1] row_mask:0xf bank_mask:0xf"
        : "+v"(v));
    return v;
}
__device__ __forceinline__ float fdot2(unsigned int h2, unsigned int w2, float acc) {
    return __builtin_amdgcn_fdot2(__builtin_bit_cast(half2v, h2),
                                  __builtin_bit_cast(half2v, w2), acc, false);
}
__device__ __forceinline__ void bar_lds() {
    asm volatile("s_waitcnt lgkmcnt(0)\n\ts_barrier" ::: "memory");
}
__device__ __forceinline__ unsigned short f2bf(float x) {
    return __builtin_bit_cast(unsigned short, __float2bfloat16(x));
}

// Fused transpose+convert of all 8 weight matrices (round 13: one launch).
struct ConvArgs {
    const float* B[8];
    unsigned short* Bt[8];
    int K[8], N[8];
    int blk0[9];   // cumulative block offsets, blk0[8] = total
};
__global__ __launch_bounds__(256) void conv_all(ConvArgs a)
{
    const int bid = blockIdx.x;
    int s = 0;
    while (s < 7 && bid >= a.blk0[s + 1]) ++s;   // scalar-uniform
    const int id = (bid - a.blk0[s]) * 256 + threadIdx.x;
    const int K = a.K[s], N = a.N[s];
    if (id < K * N) {
        const int n = id / K, k = id % K;        // write-coalesced along k
        a.Bt[s][(size_t)n * K + k] = f2bf(a.B[s][(size_t)k * N + n]);
    }
}

// C[M,N] = act(A@B + bias), A f32 [M][K] (bf16-converted in staging),
// Bt bf16 [N][K] (pre-transposed). 128x128 tile, 4 waves, 16x16x32 MFMA.
// Fragment layout (guide §3, m89-verified). Verified r11/r12 (absmax stable).
__global__ __launch_bounds__(256) void gemm_bf16t(
    const float* __restrict__ A, const unsigned short* __restrict__ Bt,
    const float* __restrict__ bias, float* __restrict__ C,
    int M, int N, int K, int ldc, int act)
{
    __shared__ unsigned short As[128][LDK];
    __shared__ unsigned short Bs[128][LDK];
    const int tid = threadIdx.x;
    const int m0 = blockIdx.y * 128, n0 = blockIdx.x * 128;
    const int wv = tid >> 6, lane = tid & 63;
    const int wr = (wv >> 1) * 64, wc = (wv & 1) * 64;
    const int lr = lane & 15, lk = lane >> 4;
    const int sm = tid >> 1, skh = (tid & 1) * 16;   // staging: row, k-half
    f32x4 acc[4][4] = {};
    for (int k0 = 0; k0 < K; k0 += 32) {
        const float* ga = &A[(size_t)(m0 + sm) * K + k0 + skh];
        float4 f0 = *(const float4*)(ga + 0);
        float4 f1 = *(const float4*)(ga + 4);
        float4 f2 = *(const float4*)(ga + 8);
        float4 f3 = *(const float4*)(ga + 12);
        const float fa[16] = {f0.x,f0.y,f0.z,f0.w, f1.x,f1.y,f1.z,f1.w,
                              f2.x,f2.y,f2.z,f2.w, f3.x,f3.y,f3.z,f3.w};
        unsigned int pk[8];
#pragma unroll
        for (int e = 0; e < 8; ++e)
            pk[e] = (unsigned int)f2bf(fa[2*e]) | ((unsigned int)f2bf(fa[2*e+1]) << 16);
        *(uint4*)&As[sm][skh]     = make_uint4(pk[0], pk[1], pk[2], pk[3]);
        *(uint4*)&As[sm][skh + 8] = make_uint4(pk[4], pk[5], pk[6], pk[7]);
        const uint4* gb = (const uint4*)&Bt[(size_t)(n0 + sm) * K + k0 + skh];
        *(uint4*)&Bs[sm][skh]     = gb[0];
        *(uint4*)&Bs[sm][skh + 8] = gb[1];
        __syncthreads();
        bf16x8 af[4], bfr[4];
#pragma unroll
        for (int f = 0; f < 4; ++f) {
            af[f]  = *(const bf16x8*)&As[wr + f * 16 + lr][lk * 8];
            bfr[f] = *(const bf16x8*)&Bs[wc + f * 16 + lr][lk * 8];
        }
#pragma unroll
        for (int i = 0; i < 4; ++i)
#pragma unroll
            for (int j = 0; j < 4; ++j)
                acc[i][j] = __builtin_amdgcn_mfma_f32_16x16x32_bf16(
                    af[i], bfr[j], acc[i][j], 0, 0, 0);
        __syncthreads();
    }
#pragma unroll
    for (int i = 0; i < 4; ++i)
#pragma unroll
        for (int j = 0; j < 4; ++j)
#pragma unroll
            for (int r = 0; r < 4; ++r) {
                const int row = m0 + wr + i * 16 + lk * 4 + r;
                const int col = n0 + wc + j * 16 + lr;
                float v = acc[i][j][r] + bias[col];
                if (act) v = fmaxf(v, 0.f);
                C[(size_t)row * ldc + col] = v;
            }
}

// Sequential GRU scan (round-10 structure + r13 fused qsum): 256 threads,
// 4 waves 1/SIMD, quad-K-split, f16 dot2 matvec, register-carried hp,
// lgkm-only barrier, PF-deep GI prefetch. ~994 cyc/step before r13.
__global__ __launch_bounds__(256)
__attribute__((amdgpu_waves_per_eu(1, 1)))
void gru_scan(
    const float* __restrict__ GI, const float* __restrict__ Whh,
    const float* __restrict__ bhh, const float* __restrict__ h0,
    double* __restrict__ esum_out, float* __restrict__ hfinal_out,
    float* __restrict__ D_out, int T)
{
    __shared__ unsigned short h16[2][HDIM];
    const int tid = threadIdx.x;
    const int j = tid >> 2;
    const int g = tid & 3;
    const int qa = 2 * j, qb = 2 * j + 1;
    const int myq = (g & 2) ? qb : qa;
    const int colS = ((g & 1) ? HDIM : 0) + myq;
    const int colT = 2 * HDIM + myq;
    unsigned int w[96];
#pragma unroll
    for (int c6 = 0; c6 < 6; ++c6) {
        const int cc = (c6 % 3) * HDIM + ((c6 < 3) ? qa : qb);
#pragma unroll
        for (int p2 = 0; p2 < 16; ++p2) {
            const int k = 32 * g + 2 * p2;
            const _Float16 lo = (_Float16)Whh[(size_t)k * G3 + cc];
            const _Float16 hi = (_Float16)Whh[(size_t)(k + 1) * G3 + cc];
            w[c6 * 16 + p2] = (unsigned int)__builtin_bit_cast(unsigned short, lo)
                            | ((unsigned int)__builtin_bit_cast(unsigned short, hi) << 16);
        }
    }
#pragma unroll
    for (int p = 0; p < 96; ++p) asm volatile("" : "+v"(w[p]));
    const float bS = bhh[colS];
    const float bT = bhh[colT];
    if (tid < HDIM)
        h16[0][tid] = __builtin_bit_cast(unsigned short,
                                         (_Float16)(h0 ? h0[tid] : 0.f));
    float hp = (float)(_Float16)(h0 ? h0[myq] : 0.f);
    double esum = 0.0;
    float gS[PF], gT[PF], gSn[PF], gTn[PF];
#pragma unroll
    for (int p = 0; p < PF; ++p) {
        gS[p] = GI[(size_t)p * G3 + colS];
        gT[p] = GI[(size_t)p * G3 + colT];
    }
    __syncthreads();
    for (int t0 = 0; t0 < T; t0 += PF) {
#pragma unroll
        for (int p = 0; p < PF; ++p) {
            gSn[p] = GI[(size_t)(t0 + PF + p) * G3 + colS];
            gTn[p] = GI[(size_t)(t0 + PF + p) * G3 + colT];
        }
#pragma unroll
        for (int p = 0; p < PF; ++p) {
            const int t = t0 + p;
            const uint4* hb = (const uint4*)h16[t & 1];
            uint4 uu[4];
#pragma unroll
            for (int pp = 0; pp < 4; ++pp) uu[pp] = hb[4 * g + pp];
            float s0 = 0.f, s1 = 0.f, s2 = 0.f, s3 = 0.f, s4 = 0.f, s5 = 0.f;
#pragma unroll
            for (int pp = 0; pp < 4; ++pp) {
                const unsigned int x[4] = {uu[pp].x, uu[pp].y, uu[pp].z, uu[pp].w};
#pragma unroll
                for (int i2 = 0; i2 < 4; ++i2) {
                    const int pi = 4 * pp + i2;
                    s0 = fdot2(x[i2], w[pi], s0);
                    s1 = fdot2(x[i2], w[16 + pi], s1);
                    s2 = fdot2(x[i2], w[32 + pi], s2);
                    s3 = fdot2(x[i2], w[48 + pi], s3);
                    s4 = fdot2(x[i2], w[64 + pi], s4);
                    s5 = fdot2(x[i2], w[80 + pi], s5);
                }
            }
            s0 = qsum(s0); s1 = qsum(s1); s2 = qsum(s2);
            s3 = qsum(s3); s4 = qsum(s4); s5 = qsum(s5);
            const float ghS = ((g & 2) ? ((g & 1) ? s4 : s3)
                                       : ((g & 1) ? s1 : s0)) + bS;
            const float ghT = ((g & 2) ? s5 : s2) + bT;
            const float s = sigm_fast(gS[p] + ghS);
            const float n = tanh_fast(gT[p] + s * ghT);
            const float z1 = bcast_q1(s);
            const float z3 = bcast_q3(s);
            const float z = (g & 2) ? z3 : z1;
            const float hn = z * (hp - n) + n;
            if (!(g & 1)) {
                h16[(t + 1) & 1][myq] =
                    __builtin_bit_cast(unsigned short, (_Float16)hn);
                esum += (double)hn;
                if (D_out) D_out[(size_t)t * HDIM + myq] = hn;
            }
            hp = (float)(_Float16)hn;
            bar_lds();
        }
#pragma unroll
        for (int p = 0; p < PF; ++p) { gS[p] = gSn[p]; gT[p] = gTn[p]; }
    }
    if (!(g & 1)) {
        if (esum_out) esum_out[myq] = esum;
        if (hfinal_out) hfinal_out[myq] = hp;
    }
}

// c2[j] = b_comb[j] + sum_k esum[k] * W_comb[128+k][j]
__global__ void prep_dec(const double* __restrict__ esum, const float* __restrict__ W_comb,
                         const float* __restrict__ b_comb, float* __restrict__ c2)
{
    __shared__ double es[HDIM];
    const int j = threadIdx.x;
    es[j] = esum[j];
    __syncthreads();
    double acc = (double)b_comb[j];
    for (int k = 0; k < HDIM; ++k)
        acc += es[k] * (double)W_comb[(HDIM + k) * HDIM + j];
    c2[j] = (float)acc;
}

// blocks [0,1024): out[row] = sigmoid(D[row].Wout + b); blocks >=1024: copy.
__global__ __launch_bounds__(256) void epilogue(
    const float* __restrict__ D, const float* __restrict__ Wout,
    const float* __restrict__ b_out, const float* __restrict__ lab,
    const float* __restrict__ wt, float* __restrict__ out)
{
    const int bid = blockIdx.x;
    if (bid < 1024) {
        const int row = (bid * 256 + threadIdx.x) >> 6;
        const int lane = threadIdx.x & 63;
        float v = D[(size_t)row * HDIM + lane] * Wout[lane]
                + D[(size_t)row * HDIM + 64 + lane] * Wout[64 + lane];
#pragma unroll
        for (int s = 32; s > 0; s >>= 1) v += __shfl_down(v, s);
        if (lane == 0) out[row] = sigm(v + b_out[0]);
    } else {
        const int i = (bid - 1024) * 256 + threadIdx.x;   // 0..8191
        out[NBOX + i] = (i < NBOX) ? lab[i] : wt[i - NBOX];
    }
}

extern "C" void kernel_launch(void* const* d_in, const int* in_sizes, int n_in,
                              void* d_out, int out_size, void* d_ws, size_t ws_size,
                              hipStream_t stream)
{
    const float* boxes_feature = (const float*)d_in[0];
    const float* boxes_score   = (const float*)d_in[1];
    const float* boxes_box     = (const float*)d_in[2];
    const float* boxes_label   = (const float*)d_in[3];
    const float* boxes_weight  = (const float*)d_in[4];
    const float* W_appear = (const float*)d_in[6];
    const float* b_appear = (const float*)d_in[7];
    const float* W_s1     = (const float*)d_in[8];
    const float* b_s1     = (const float*)d_in[9];
    const float* W_s2     = (const float*)d_in[10];
    const float* b_s2     = (const float*)d_in[11];
    const float* W_box    = (const float*)d_in[12];
    const float* b_box    = (const float*)d_in[13];
    const float* W_all    = (const float*)d_in[14];
    const float* b_all    = (const float*)d_in[15];
    const float* enc_Wih  = (const float*)d_in[16];
    const float* enc_Whh  = (const float*)d_in[17];
    const float* enc_bih  = (const float*)d_in[18];
    const float* enc_bhh  = (const float*)d_in[19];
    const float* dec_Wih  = (const float*)d_in[20];
    const float* dec_Whh  = (const float*)d_in[21];
    const float* dec_bih  = (const float*)d_in[22];
    const float* dec_bhh  = (const float*)d_in[23];
    // d_in[24] W_attn, d_in[25] b_attn: no effect (softmax over singleton)
    const float* W_comb   = (const float*)d_in[26];
    const float* b_comb   = (const float*)d_in[27];
    const float* W_out    = (const float*)d_in[28];
    const float* b_out    = (const float*)d_in[29];

    float* out = (float*)d_out;
    float* ws = (float*)d_ws;
    size_t o = 0;
    float* T1   = ws + o; o += (size_t)NBOX * 512;      // score@W_s1+b (LINEAR)
    float* XCAT = ws + o; o += (size_t)NBOX * G3;
    float* X    = ws + o; o += (size_t)NBOX * HDIM;
    float* GIE  = ws + o; o += (size_t)(NBOX + PF) * G3;  // padded for prefetch
    float* GID  = ws + o; o += (size_t)(NBOX + PF) * G3;
    float* DIN  = ws + o; o += (size_t)NBOX * HDIM;
    float* D    = ws + o; o += (size_t)NBOX * HDIM;
    o = (o + 1) & ~(size_t)1;
    double* esum = (double*)(ws + o); o += 256;
    float* henc = ws + o; o += 128;
    float* c2   = ws + o; o += 128;

    // bf16-transposed weights ALIASED into regions written only later:
    //  - GIE region: W_s1^T, W_appear^T, W_s2^T, W_box^T, W_all^T (consumed
    //    by phase-1 GEMMs before GIE is written).
    //  - GID region: enc_Wih^T, W_comb^T (consumed before GID written).
    //  - D region: dec_Wih^T (consumed before decoder scan writes D).
    unsigned short* ws1t   = (unsigned short*)GIE;            // 2560*512
    unsigned short* wappt  = ws1t + 1310720;                  // 1024*128
    unsigned short* ws2t   = wappt + 131072;                  // 512*128
    unsigned short* wboxt  = ws2t + 65536;                    // 320*128
    unsigned short* wallt  = wboxt + 40960;                   // 384*128
    unsigned short* encwt  = (unsigned short*)GID;            // 128*384
    unsigned short* wcombt = encwt + 49152;                   // 128*128
    unsigned short* decwt  = (unsigned short*)D;              // 128*384

    // ---- all 8 weight transposes in ONE launch ----
    ConvArgs ca;
    ca.B[0]=W_s1;    ca.Bt[0]=ws1t;   ca.K[0]=2560; ca.N[0]=512;
    ca.B[1]=W_appear;ca.Bt[1]=wappt;  ca.K[1]=1024; ca.N[1]=128;
    ca.B[2]=W_s2;    ca.Bt[2]=ws2t;   ca.K[2]=512;  ca.N[2]=128;
    ca.B[3]=W_box;   ca.Bt[3]=wboxt;  ca.K[3]=320;  ca.N[3]=128;
    ca.B[4]=W_all;   ca.Bt[4]=wallt;  ca.K[4]=384;  ca.N[4]=128;
    ca.B[5]=enc_Wih; ca.Bt[5]=encwt;  ca.K[5]=128;  ca.N[5]=384;
    ca.B[6]=W_comb;  ca.Bt[6]=wcombt; ca.K[6]=128;  ca.N[6]=128;
    ca.B[7]=dec_Wih; ca.Bt[7]=decwt;  ca.K[7]=128;  ca.N[7]=384;
    {
        int acc_blk = 0;
        for (int s = 0; s < 8; ++s) {
            ca.blk0[s] = acc_blk;
            acc_blk += (ca.K[s] * ca.N[s] + 255) / 256;
        }
        ca.blk0[8] = acc_blk;
        conv_all<<<acc_blk, 256, 0, stream>>>(ca);
    }

    // ---- phase 1: feature GEMMs (all MFMA) ----
    gemm_bf16t<<<dim3(4, 32), 256, 0, stream>>>(
        boxes_score, ws1t, b_s1, T1, NBOX, 512, 2560, 512, 0);   // LINEAR
    gemm_bf16t<<<dim3(1, 32), 256, 0, stream>>>(
        boxes_feature, wappt, b_appear, XCAT + 0, NBOX, 128, 1024, G3, 1);
    gemm_bf16t<<<dim3(1, 32), 256, 0, stream>>>(
        T1, ws2t, b_s2, XCAT + HDIM, NBOX, 128, 512, G3, 1);
    gemm_bf16t<<<dim3(1, 32), 256, 0, stream>>>(
        boxes_box, wboxt, b_box, XCAT + 2 * HDIM, NBOX, 128, 320, G3, 1);
    gemm_bf16t<<<dim3(1, 32), 256, 0, stream>>>(
        XCAT, wallt, b_all, X, NBOX, 128, 384, HDIM, 1);

    // ---- encoder ----
    gemm_bf16t<<<dim3(3, 32), 256, 0, stream>>>(
        X, encwt, enc_bih, GIE, NBOX, 384, 128, G3, 0);
    gru_scan<<<1, 256, 0, stream>>>(GIE, enc_Whh, enc_bhh, nullptr,
                                    esum, henc, nullptr, NBOX);

    // ---- decoder prep (applied = esum constant across steps) ----
    prep_dec<<<1, 128, 0, stream>>>(esum, W_comb, b_comb, c2);
    gemm_bf16t<<<dim3(1, 32), 256, 0, stream>>>(
        X, wcombt, c2, DIN, NBOX, 128, 128, HDIM, 1);
    gemm_bf16t<<<dim3(3, 32), 256, 0, stream>>>(
        DIN, decwt, dec_bih, GID, NBOX, 384, 128, G3, 0);

    // ---- decoder scan ----
    gru_scan<<<1, 256, 0, stream>>>(GID, dec_Whh, dec_bhh, henc,
                                    nullptr, nullptr, D, NBOX);

    // ---- epilogue (row-dot + label/weight copy fused) ----
    epilogue<<<1024 + 32, 256, 0, stream>>>(D, W_out, b_out,
                                            boxes_label, boxes_weight, out);
}

// Round 14
// 3357.422 us; speedup vs baseline: 1.5505x; 1.0004x over previous
//
#include <hip/hip_runtime.h>
#include <hip/hip_bf16.h>
#include <math.h>

#define NBOX 4096
#define HDIM 128
#define G3   384   // 3*H
#define PF   8     // GI prefetch depth (steps)

typedef _Float16 half2v __attribute__((ext_vector_type(2)));
typedef short bf16x8 __attribute__((ext_vector_type(8)));
typedef float f32x4 __attribute__((ext_vector_type(4)));
#define LDK 40     // LDS row stride in shorts (80B, 16B-aligned, 2-way banks)

__device__ __forceinline__ float sigm(float x) { return 1.f / (1.f + expf(-x)); }
__device__ __forceinline__ float sigm_fast(float x) {
    return __builtin_amdgcn_rcpf(1.f + __expf(-x));
}
// inf-safe clampless tanh: e^{2x}->inf gives 1-0=1; ->0 gives 1-2=-1.
__device__ __forceinline__ float tanh_fast(float x) {
    const float e2 = __expf(2.f * x);
    return 1.f - 2.f * __builtin_amdgcn_rcpf(e2 + 1.f);
}
__device__ __forceinline__ float bcast_q1(float x) {
    return __int_as_float(__builtin_amdgcn_mov_dpp(__float_as_int(x), 0x55, 0xF, 0xF, false));
}
__device__ __forceinline__ float bcast_q3(float x) {
    return __int_as_float(__builtin_amdgcn_mov_dpp(__float_as_int(x), 0xFF, 0xF, 0xF, false));
}
// quad all-reduce sum, fused dpp-add (r13; −117us/scan verified)
__device__ __forceinline__ float qsum(float v) {
    asm("v_add_f32_dpp %0, %0, %0 quad_perm:[1,0,3,2] row_mask:0xf bank_mask:0xf"
        : "+v"(v));
    asm("v_add_f32_dpp %0, %0, %0 quad_perm:[2,3,0,1] row_mask:0xf bank_mask:0xf"
        : "+v"(v));
    return v;
}
__device__ __forceinline__ float fdot2(unsigned int h2, unsigned int w2, float acc) {
    return __builtin_amdgcn_fdot2(__builtin_bit_cast(half2v, h2),
                                  __builtin_bit_cast(half2v, w2), acc, false);
}
__device__ __forceinline__ void bar_lds() {
    asm volatile("s_waitcnt lgkmcnt(0)\n\ts_barrier" ::: "memory");
}
__device__ __forceinline__ unsigned short f2bf(float x) {
    return __builtin_bit_cast(unsigned short, __float2bfloat16(x));
}

// Fused transpose+convert of 7 small weight matrices (one launch).
struct ConvArgs {
    const float* B[7];
    unsigned short* Bt[7];
    int K[7], N[7];
    int blk0[8];   // cumulative block offsets, blk0[7] = total
};
__global__ __launch_bounds__(256) void conv_all(ConvArgs a)
{
    const int bid = blockIdx.x;
    int s = 0;
    while (s < 6 && bid >= a.blk0[s + 1]) ++s;   // scalar-uniform
    const int id = (bid - a.blk0[s]) * 256 + threadIdx.x;
    const int K = a.K[s], N = a.N[s];
    if (id < K * N) {
        const int n = id / K, k = id % K;        // write-coalesced along k
        a.Bt[s][(size_t)n * K + k] = f2bf(a.B[s][(size_t)k * N + n]);
    }
}

// single transpose+convert (for Wfused, which is produced on-device)
__global__ __launch_bounds__(256) void conv_bt(
    const float* __restrict__ B, unsigned short* __restrict__ Bt, int K, int N)
{
    const int id = blockIdx.x * 256 + threadIdx.x;
    if (id < K * N) {
        const int n = id / K, k = id % K;
        Bt[(size_t)n * K + k] = f2bf(B[(size_t)k * N + n]);
    }
}

// bfused[j] = b_s2[j] + sum_c b_s1[c]*W_s2[c][j]; also writes a zero bias.
__global__ void bias_fuse(const float* __restrict__ b_s1, const float* __restrict__ W_s2,
                          const float* __restrict__ b_s2, float* __restrict__ bfused,
                          float* __restrict__ zero128)
{
    const int j = threadIdx.x;   // 128
    double acc = (double)b_s2[j];
    for (int c = 0; c < 512; ++c)
        acc += (double)b_s1[c] * (double)W_s2[c * HDIM + j];
    bfused[j] = (float)acc;
    zero128[j] = 0.f;
}

// C[M,N] = act(A@B + bias), A f32 [M][K] (bf16-converted in staging),
// Bt bf16 [N][K] (pre-transposed). 128x128 tile, 4 waves, 16x16x32 MFMA.
// Fragment layout (guide §3, m89-verified). Verified r11/r12 (absmax stable).
__global__ __launch_bounds__(256) void gemm_bf16t(
    const float* __restrict__ A, const unsigned short* __restrict__ Bt,
    const float* __restrict__ bias, float* __restrict__ C,
    int M, int N, int K, int ldc, int act)
{
    __shared__ unsigned short As[128][LDK];
    __shared__ unsigned short Bs[128][LDK];
    const int tid = threadIdx.x;
    const int m0 = blockIdx.y * 128, n0 = blockIdx.x * 128;
    const int wv = tid >> 6, lane = tid & 63;
    const int wr = (wv >> 1) * 64, wc = (wv & 1) * 64;
    const int lr = lane & 15, lk = lane >> 4;
    const int sm = tid >> 1, skh = (tid & 1) * 16;   // staging: row, k-half
    f32x4 acc[4][4] = {};
    for (int k0 = 0; k0 < K; k0 += 32) {
        const float* ga = &A[(size_t)(m0 + sm) * K + k0 + skh];
        float4 f0 = *(const float4*)(ga + 0);
        float4 f1 = *(const float4*)(ga + 4);
        float4 f2 = *(const float4*)(ga + 8);
        float4 f3 = *(const float4*)(ga + 12);
        const float fa[16] = {f0.x,f0.y,f0.z,f0.w, f1.x,f1.y,f1.z,f1.w,
                              f2.x,f2.y,f2.z,f2.w, f3.x,f3.y,f3.z,f3.w};
        unsigned int pk[8];
#pragma unroll
        for (int e = 0; e < 8; ++e)
            pk[e] = (unsigned int)f2bf(fa[2*e]) | ((unsigned int)f2bf(fa[2*e+1]) << 16);
        *(uint4*)&As[sm][skh]     = make_uint4(pk[0], pk[1], pk[2], pk[3]);
        *(uint4*)&As[sm][skh + 8] = make_uint4(pk[4], pk[5], pk[6], pk[7]);
        const uint4* gb = (const uint4*)&Bt[(size_t)(n0 + sm) * K + k0 + skh];
        *(uint4*)&Bs[sm][skh]     = gb[0];
        *(uint4*)&Bs[sm][skh + 8] = gb[1];
        __syncthreads();
        bf16x8 af[4], bfr[4];
#pragma unroll
        for (int f = 0; f < 4; ++f) {
            af[f]  = *(const bf16x8*)&As[wr + f * 16 + lr][lk * 8];
            bfr[f] = *(const bf16x8*)&Bs[wc + f * 16 + lr][lk * 8];
        }
#pragma unroll
        for (int i = 0; i < 4; ++i)
#pragma unroll
            for (int j = 0; j < 4; ++j)
                acc[i][j] = __builtin_amdgcn_mfma_f32_16x16x32_bf16(
                    af[i], bfr[j], acc[i][j], 0, 0, 0);
        __syncthreads();
    }
#pragma unroll
    for (int i = 0; i < 4; ++i)
#pragma unroll
        for (int j = 0; j < 4; ++j)
#pragma unroll
            for (int r = 0; r < 4; ++r) {
                const int row = m0 + wr + i * 16 + lk * 4 + r;
                const int col = n0 + wc + j * 16 + lr;
                float v = acc[i][j][r] + bias[col];
                if (act) v = fmaxf(v, 0.f);
                C[(size_t)row * ldc + col] = v;
            }
}

// Sequential GRU scan (round-10 structure + r13 qsum + r14 tanh/hp trims):
// 256 threads, 4 waves 1/SIMD, quad-K-split, f16 dot2 matvec, f32
// register-carried hp, lgkm-only barrier, PF-deep GI prefetch.
__global__ __launch_bounds__(256)
__attribute__((amdgpu_waves_per_eu(1, 1)))
void gru_scan(
    const float* __restrict__ GI, const float* __restrict__ Whh,
    const float* __restrict__ bhh, const float* __restrict__ h0,
    double* __restrict__ esum_out, float* __restrict__ hfinal_out,
    float* __restrict__ D_out, int T)
{
    __shared__ unsigned short h16[2][HDIM];
    const int tid = threadIdx.x;
    const int j = tid >> 2;
    const int g = tid & 3;
    const int qa = 2 * j, qb = 2 * j + 1;
    const int myq = (g & 2) ? qb : qa;
    const int colS = ((g & 1) ? HDIM : 0) + myq;
    const int colT = 2 * HDIM + myq;
    unsigned int w[96];
#pragma unroll
    for (int c6 = 0; c6 < 6; ++c6) {
        const int cc = (c6 % 3) * HDIM + ((c6 < 3) ? qa : qb);
#pragma unroll
        for (int p2 = 0; p2 < 16; ++p2) {
            const int k = 32 * g + 2 * p2;
            const _Float16 lo = (_Float16)Whh[(size_t)k * G3 + cc];
            const _Float16 hi = (_Float16)Whh[(size_t)(k + 1) * G3 + cc];
            w[c6 * 16 + p2] = (unsigned int)__builtin_bit_cast(unsigned short, lo)
                            | ((unsigned int)__builtin_bit_cast(unsigned short, hi) << 16);
        }
    }
#pragma unroll
    for (int p = 0; p < 96; ++p) asm volatile("" : "+v"(w[p]));
    const float bS = bhh[colS];
    const float bT = bhh[colT];
    if (tid < HDIM)
        h16[0][tid] = __builtin_bit_cast(unsigned short,
                                         (_Float16)(h0 ? h0[tid] : 0.f));
    float hp = h0 ? h0[myq] : 0.f;      // f32 carry (r14: closer to ref, -1 cvt)
    double esum = 0.0;
    float gS[PF], gT[PF], gSn[PF], gTn[PF];
#pragma unroll
    for (int p = 0; p < PF; ++p) {
        gS[p] = GI[(size_t)p * G3 + colS];
        gT[p] = GI[(size_t)p * G3 + colT];
    }
    __syncthreads();
    for (int t0 = 0; t0 < T; t0 += PF) {
#pragma unroll
        for (int p = 0; p < PF; ++p) {
            gSn[p] = GI[(size_t)(t0 + PF + p) * G3 + colS];
            gTn[p] = GI[(size_t)(t0 + PF + p) * G3 + colT];
        }
#pragma unroll
        for (int p = 0; p < PF; ++p) {
            const int t = t0 + p;
            const uint4* hb = (const uint4*)h16[t & 1];
            uint4 uu[4];
#pragma unroll
            for (int pp = 0; pp < 4; ++pp) uu[pp] = hb[4 * g + pp];
            float s0 = 0.f, s1 = 0.f, s2 = 0.f, s3 = 0.f, s4 = 0.f, s5 = 0.f;
#pragma unroll
            for (int pp = 0; pp < 4; ++pp) {
                const unsigned int x[4] = {uu[pp].x, uu[pp].y, uu[pp].z, uu[pp].w};
#pragma unroll
                for (int i2 = 0; i2 < 4; ++i2) {
                    const int pi = 4 * pp + i2;
                    s0 = fdot2(x[i2], w[pi], s0);
                    s1 = fdot2(x[i2], w[16 + pi], s1);
                    s2 = fdot2(x[i2], w[32 + pi], s2);
                    s3 = fdot2(x[i2], w[48 + pi], s3);
                    s4 = fdot2(x[i2], w[64 + pi], s4);
                    s5 = fdot2(x[i2], w[80 + pi], s5);
                }
            }
            s0 = qsum(s0); s1 = qsum(s1); s2 = qsum(s2);
            s3 = qsum(s3); s4 = qsum(s4); s5 = qsum(s5);
            const float ghS = ((g & 2) ? ((g & 1) ? s4 : s3)
                                       : ((g & 1) ? s1 : s0)) + bS;
            const float ghT = ((g & 2) ? s5 : s2) + bT;
            const float s = sigm_fast(gS[p] + ghS);
            const float n = tanh_fast(gT[p] + s * ghT);
            const float z1 = bcast_q1(s);
            const float z3 = bcast_q3(s);
            const float z = (g & 2) ? z3 : z1;
            const float hn = z * (hp - n) + n;
            if (!(g & 1)) {
                h16[(t + 1) & 1][myq] =
                    __builtin_bit_cast(unsigned short, (_Float16)hn);
                esum += (double)hn;
                if (D_out) D_out[(size_t)t * HDIM + myq] = hn;
            }
            hp = hn;
            bar_lds();
        }
#pragma unroll
        for (int p = 0; p < PF; ++p) { gS[p] = gSn[p]; gT[p] = gTn[p]; }
    }
    if (!(g & 1)) {
        if (esum_out) esum_out[myq] = esum;
        if (hfinal_out) hfinal_out[myq] = hp;
    }
}

// c2[j] = b_comb[j] + sum_k esum[k] * W_comb[128+k][j]
__global__ void prep_dec(const double* __restrict__ esum, const float* __restrict__ W_comb,
                         const float* __restrict__ b_comb, float* __restrict__ c2)
{
    __shared__ double es[HDIM];
    const int j = threadIdx.x;
    es[j] = esum[j];
    __syncthreads();
    double acc = (double)b_comb[j];
    for (int k = 0; k < HDIM; ++k)
        acc += es[k] * (double)W_comb[(HDIM + k) * HDIM + j];
    c2[j] = (float)acc;
}

// blocks [0,1024): out[row] = sigmoid(D[row].Wout + b); blocks >=1024: copy.
__global__ __launch_bounds__(256) void epilogue(
    const float* __restrict__ D, const float* __restrict__ Wout,
    const float* __restrict__ b_out, const float* __restrict__ lab,
    const float* __restrict__ wt, float* __restrict__ out)
{
    const int bid = blockIdx.x;
    if (bid < 1024) {
        const int row = (bid * 256 + threadIdx.x) >> 6;
        const int lane = threadIdx.x & 63;
        float v = D[(size_t)row * HDIM + lane] * Wout[lane]
                + D[(size_t)row * HDIM + 64 + lane] * Wout[64 + lane];
#pragma unroll
        for (int s = 32; s > 0; s >>= 1) v += __shfl_down(v, s);
        if (lane == 0) out[row] = sigm(v + b_out[0]);
    } else {
        const int i = (bid - 1024) * 256 + threadIdx.x;   // 0..8191
        out[NBOX + i] = (i < NBOX) ? lab[i] : wt[i - NBOX];
    }
}

extern "C" void kernel_launch(void* const* d_in, const int* in_sizes, int n_in,
                              void* d_out, int out_size, void* d_ws, size_t ws_size,
                              hipStream_t stream)
{
    const float* boxes_feature = (const float*)d_in[0];
    const float* boxes_score   = (const float*)d_in[1];
    const float* boxes_box     = (const float*)d_in[2];
    const float* boxes_label   = (const float*)d_in[3];
    const float* boxes_weight  = (const float*)d_in[4];
    const float* W_appear = (const float*)d_in[6];
    const float* b_appear = (const float*)d_in[7];
    const float* W_s1     = (const float*)d_in[8];
    const float* b_s1     = (const float*)d_in[9];
    const float* W_s2     = (const float*)d_in[10];
    const float* b_s2     = (const float*)d_in[11];
    const float* W_box    = (const float*)d_in[12];
    const float* b_box    = (const float*)d_in[13];
    const float* W_all    = (const float*)d_in[14];
    const float* b_all    = (const float*)d_in[15];
    const float* enc_Wih  = (const float*)d_in[16];
    const float* enc_Whh  = (const float*)d_in[17];
    const float* enc_bih  = (const float*)d_in[18];
    const float* enc_bhh  = (const float*)d_in[19];
    const float* dec_Wih  = (const float*)d_in[20];
    const float* dec_Whh  = (const float*)d_in[21];
    const float* dec_bih  = (const float*)d_in[22];
    const float* dec_bhh  = (const float*)d_in[23];
    // d_in[24] W_attn, d_in[25] b_attn: no effect (softmax over singleton)
    const float* W_comb   = (const float*)d_in[26];
    const float* b_comb   = (const float*)d_in[27];
    const float* W_out    = (const float*)d_in[28];
    const float* b_out    = (const float*)d_in[29];

    float* out = (float*)d_out;
    float* ws = (float*)d_ws;
    size_t o = 0;
    float* T1   = ws + o; o += (size_t)NBOX * 512;      // now scratch (fusion)
    float* XCAT = ws + o; o += (size_t)NBOX * G3;
    float* X    = ws + o; o += (size_t)NBOX * HDIM;
    float* GIE  = ws + o; o += (size_t)(NBOX + PF) * G3;  // padded for prefetch
    float* GID  = ws + o; o += (size_t)(NBOX + PF) * G3;
    float* DIN  = ws + o; o += (size_t)NBOX * HDIM;
    float* D    = ws + o; o += (size_t)NBOX * HDIM;
    o = (o + 1) & ~(size_t)1;
    double* esum = (double*)(ws + o); o += 256;
    float* henc = ws + o; o += 128;
    float* c2   = ws + o; o += 128;

    // r14 fusion scratch in the dead T1 region:
    float* wf32          = T1;                            // Wfused f32 [2560][128]
    unsigned short* wfut = (unsigned short*)(T1 + 327680);// Wfused^T bf16 [128][2560]
    float* zero128       = T1 + 491520;
    float* bfused        = T1 + 491648;
    // small transposed weights aliased into later-written regions:
    unsigned short* wappt  = (unsigned short*)GIE;        // 1024*128
    unsigned short* ws2t   = wappt + 131072;              // 512*128
    unsigned short* wboxt  = ws2t + 65536;                // 320*128
    unsigned short* wallt  = wboxt + 40960;               // 384*128
    unsigned short* encwt  = (unsigned short*)GID;        // 128*384
    unsigned short* wcombt = encwt + 49152;               // 128*128
    unsigned short* decwt  = (unsigned short*)D;          // 128*384

    // ---- weight transposes (one launch, 7 matrices) ----
    ConvArgs ca;
    ca.B[0]=W_appear; ca.Bt[0]=wappt;  ca.K[0]=1024; ca.N[0]=128;
    ca.B[1]=W_s2;     ca.Bt[1]=ws2t;   ca.K[1]=512;  ca.N[1]=128;
    ca.B[2]=W_box;    ca.Bt[2]=wboxt;  ca.K[2]=320;  ca.N[2]=128;
    ca.B[3]=W_all;    ca.Bt[3]=wallt;  ca.K[3]=384;  ca.N[3]=128;
    ca.B[4]=enc_Wih;  ca.Bt[4]=encwt;  ca.K[4]=128;  ca.N[4]=384;
    ca.B[5]=W_comb;   ca.Bt[5]=wcombt; ca.K[5]=128;  ca.N[5]=128;
    ca.B[6]=dec_Wih;  ca.Bt[6]=decwt;  ca.K[6]=128;  ca.N[6]=384;
    {
        int acc_blk = 0;
        for (int s = 0; s < 7; ++s) {
            ca.blk0[s] = acc_blk;
            acc_blk += (ca.K[s] * ca.N[s] + 255) / 256;
        }
        ca.blk0[7] = acc_blk;
        conv_all<<<acc_blk, 256, 0, stream>>>(ca);
    }
    bias_fuse<<<1, 128, 0, stream>>>(b_s1, W_s2, b_s2, bfused, zero128);

    // ---- Wfused = W_s1 @ W_s2  (algebraic collapse of the T1 path:
    //      inner matmul is LINEAR, so es = relu(score@Wfused + bfused)) ----
    gemm_bf16t<<<dim3(1, 2560 / 128), 256, 0, stream>>>(
        W_s1, ws2t, zero128, wf32, 2560, 128, 512, 128, 0);
    conv_bt<<<(2560 * 128 + 255) / 256, 256, 0, stream>>>(wf32, wfut, 2560, 128);

    // ---- phase 1: feature GEMMs (all MFMA) ----
    gemm_bf16t<<<dim3(1, 32), 256, 0, stream>>>(
        boxes_score, wfut, bfused, XCAT + HDIM, NBOX, 128, 2560, G3, 1);  // es
    gemm_bf16t<<<dim3(1, 32), 256, 0, stream>>>(
        boxes_feature, wappt, b_appear, XCAT + 0, NBOX, 128, 1024, G3, 1); // ef
    gemm_bf16t<<<dim3(1, 32), 256, 0, stream>>>(
        boxes_box, wboxt, b_box, XCAT + 2 * HDIM, NBOX, 128, 320, G3, 1);  // eb
    gemm_bf16t<<<dim3(1, 32), 256, 0, stream>>>(
        XCAT, wallt, b_all, X, NBOX, 128, 384, HDIM, 1);                   // X

    // ---- encoder ----
    gemm_bf16t<<<dim3(3, 32), 256, 0, stream>>>(
        X, encwt, enc_bih, GIE, NBOX, 384, 128, G3, 0);
    gru_scan<<<1, 256, 0, stream>>>(GIE, enc_Whh, enc_bhh, nullptr,
                                    esum, henc, nullptr, NBOX);

    // ---- decoder prep (applied = esum constant across steps) ----
    prep_dec<<<1, 128, 0, stream>>>(esum, W_comb, b_comb, c2);
    gemm_bf16t<<<dim3(1, 32), 256, 0, stream>>>(
        X, wcombt, c2, DIN, NBOX, 128, 128, HDIM, 1);
    gemm_bf16t<<<dim3(3, 32), 256, 0, stream>>>(
        DIN, decwt, dec_bih, GID, NBOX, 384, 128, G3, 0);

    // ---- decoder scan ----
    gru_scan<<<1, 256, 0, stream>>>(GID, dec_Whh, dec_bhh, henc,
                                    nullptr, nullptr, D, NBOX);

    // ---- epilogue (row-dot + label/weight copy fused) ----
    epilogue<<<1024 + 32, 256, 0, stream>>>(D, W_out, b_out,
                                            boxes_label, boxes_weight, out);
}